// Round 5
// baseline (1605.713 us; speedup 1.0000x reference)
//
#include <hip/hip_runtime.h>
#include <cstddef>

#define NB 65536
#define SL 5

__device__ __forceinline__ float sigm(float x)   { return 1.0f / (1.0f + __expf(-x)); }
__device__ __forceinline__ float tanh_f(float x) { return 2.0f / (1.0f + __expf(-2.0f * x)) - 1.0f; }

// ---------------------------------------------------------------------------
// Phase A: thread = (b, s, node). Only m_all is exchanged between the 4 node
// threads (12KB LDS); GRU weights are wave-uniform s_loads.
// Writes x transposed as xt[s][feat=d*4+node][b] for coalesced phase-B reads.
// (unchanged from round 4 — single-variable experiment on the LSTM kernel)
// ---------------------------------------------------------------------------
__global__ __launch_bounds__(256) void msg_pass_kernel(
    const float* __restrict__ nf, const float* __restrict__ pos,
    const float* __restrict__ att,
    const float* __restrict__ msg_w, const float* __restrict__ msg_b,
    const float* __restrict__ gw_ih, const float* __restrict__ gw_hh,
    const float* __restrict__ gb_ih, const float* __restrict__ gb_hh,
    float* __restrict__ xt)
{
  __shared__ float ma_lds[12][256];
  const int tid  = threadIdx.x;
  const int t    = blockIdx.x * 256 + tid;
  const int node = t & 3;
  const int rem  = t >> 2;            // = s*NB + b
  const int s    = rem >> 16;         // NB = 65536
  const int b    = rem & (NB - 1);
  const size_t ibase = ((size_t)(b * SL + s) * 4 + node) * 6;

  float h[12];
  {
    const float2* n2 = (const float2*)(nf  + ibase);
    const float2* p2 = (const float2*)(pos + ibase);
#pragma unroll
    for (int q = 0; q < 3; q++) {
      float2 v = n2[q]; h[q*2]   = v.x; h[q*2+1]   = v.y;
      float2 u = p2[q]; h[6+q*2] = u.x; h[6+q*2+1] = u.y;
    }
  }
  float ta[4];
  {
    float4 v = *(const float4*)(att + ((size_t)(b * SL + s) * 4 + node) * 4);
    ta[0] = v.x; ta[1] = v.y; ta[2] = v.z; ta[3] = v.w;
  }

#pragma unroll 1
  for (int pass = 0; pass < 2; ++pass) {
    if (pass) __syncthreads();
#pragma unroll
    for (int j = 0; j < 12; j++) {
      float a = msg_b[j];
#pragma unroll
      for (int i = 0; i < 12; i++) a = __builtin_fmaf(msg_w[j*12+i], h[i], a);
      ma_lds[j][tid] = a;
    }
    __syncthreads();
    const int base4 = tid & ~3;
    float mv[12];
#pragma unroll
    for (int j = 0; j < 12; j++) {
      mv[j] = ta[0]*ma_lds[j][base4]   + ta[1]*ma_lds[j][base4+1]
            + ta[2]*ma_lds[j][base4+2] + ta[3]*ma_lds[j][base4+3];
    }
    float hn[12];
#pragma unroll
    for (int j = 0; j < 12; j++) {
      float ar  = gb_ih[j]    + gb_hh[j];
      float az  = gb_ih[12+j] + gb_hh[12+j];
      float ani = gb_ih[24+j];
      float anh = gb_hh[24+j];
#pragma unroll
      for (int i = 0; i < 12; i++) {
        const float mvi = mv[i], hi = h[i];
        ar  = __builtin_fmaf(gw_ih[j*12+i],      mvi, ar);
        ar  = __builtin_fmaf(gw_hh[j*12+i],      hi,  ar);
        az  = __builtin_fmaf(gw_ih[(12+j)*12+i], mvi, az);
        az  = __builtin_fmaf(gw_hh[(12+j)*12+i], hi,  az);
        ani = __builtin_fmaf(gw_ih[(24+j)*12+i], mvi, ani);
        anh = __builtin_fmaf(gw_hh[(24+j)*12+i], hi,  anh);
      }
      const float r = sigm(ar), z = sigm(az);
      const float g = tanh_f(ani + r * anh);
      hn[j] = (1.0f - z) * g + z * h[j];
    }
#pragma unroll
    for (int j = 0; j < 12; j++) h[j] = hn[j];
  }

#pragma unroll
  for (int d = 0; d < 12; d++)
    xt[(size_t)(s * 48 + d * 4 + node) * NB + b] = h[d];
}

// ---------------------------------------------------------------------------
// Phase B+C: biLSTM + MLP head. Block = 64 batches x 8 waves.
// Wave w: dir = w&1, unit-group ug = w>>1 -> wave-uniform weight rows.
// NEW STRUCTURE (vs r4): j fully unrolled -> 48 gate accumulators + c[12] in
// registers (static indices); k tiled by 24 -> xk[24]/hk[24] per tile (48
// LDS reads/step instead of 576); no asm clobbers -> compiler free to
// prefetch weights under the FMA stream. Live set ~118 VGPR, no spill.
// LDS = h double-buffer only (48KB). MLP reuses h_lds[0] as scratch.
// ---------------------------------------------------------------------------
__global__ __launch_bounds__(512) void lstm_head_kernel(
    const float* __restrict__ xt,
    const float* __restrict__ wi_fw, const float* __restrict__ wh_fw,
    const float* __restrict__ bi_fw, const float* __restrict__ bh_fw,
    const float* __restrict__ wi_bw, const float* __restrict__ wh_bw,
    const float* __restrict__ bi_bw, const float* __restrict__ bh_bw,
    const float* __restrict__ e1w, const float* __restrict__ e1b,
    const float* __restrict__ e2w, const float* __restrict__ e2b,
    const float* __restrict__ e3w, const float* __restrict__ e3b,
    float* __restrict__ out)
{
  __shared__ float h_lds[2][96][64];   // [phase][dir*48+unit][batch] 48KB

  const int tid  = threadIdx.x;
  const int lane = tid & 63;
  const int w    = __builtin_amdgcn_readfirstlane(tid >> 6);  // wave id 0..7
  const int dir  = w & 1;
  const int ug   = w >> 1;             // unit group 0..3
  const int b    = blockIdx.x * 64 + lane;

  const float* __restrict__ wi = dir ? wi_bw : wi_fw;
  const float* __restrict__ wh = dir ? wh_bw : wh_fw;
  const float* __restrict__ bi = dir ? bi_bw : bi_fw;
  const float* __restrict__ bh = dir ? bh_bw : bh_fw;

  float c[12];                         // cell state: registers (static idx)
#pragma unroll
  for (int j = 0; j < 12; j++) {
    c[j] = 0.0f;
    h_lds[0][dir * 48 + ug * 12 + j][lane] = 0.0f;
  }
  __syncthreads();

#pragma unroll 1
  for (int st = 0; st < 5; ++st) {
    const int p = st & 1;
    const int s = dir ? (4 - st) : st;

    float ai[12], af[12], ag[12], ao[12];   // 48 accumulators (static idx)
#pragma unroll
    for (int j = 0; j < 12; j++) {
      const int row = ug * 12 + j;
      ai[j] = bi[row]       + bh[row];
      af[j] = bi[48 + row]  + bh[48 + row];
      ag[j] = bi[96 + row]  + bh[96 + row];
      ao[j] = bi[144 + row] + bh[144 + row];
    }

#pragma unroll 1
    for (int t = 0; t < 2; ++t) {      // k-tiles of 24
      const int kb = t * 24;
      float xk[24];
#pragma unroll
      for (int i = 0; i < 24; i++)
        xk[i] = xt[(size_t)(s * 48 + kb + i) * NB + b];
      float hk[24];
      const float* __restrict__ hrow = &h_lds[p][dir * 48 + kb][0];
#pragma unroll
      for (int i = 0; i < 24; i++) hk[i] = hrow[i * 64 + lane];

#pragma unroll
      for (int j = 0; j < 12; j++) {
        const float* __restrict__ wij = wi + (ug * 12 + j) * 48 + kb;
        const float* __restrict__ whj = wh + (ug * 12 + j) * 48 + kb;
#pragma unroll
        for (int k = 0; k < 24; k++) {
          const float xv = xk[k];
          const float hv = hk[k];
          ai[j] = __builtin_fmaf(wij[k],        xv, ai[j]);
          ai[j] = __builtin_fmaf(whj[k],        hv, ai[j]);
          af[j] = __builtin_fmaf(wij[2304 + k], xv, af[j]);
          af[j] = __builtin_fmaf(whj[2304 + k], hv, af[j]);
          ag[j] = __builtin_fmaf(wij[4608 + k], xv, ag[j]);
          ag[j] = __builtin_fmaf(whj[4608 + k], hv, ag[j]);
          ao[j] = __builtin_fmaf(wij[6912 + k], xv, ao[j]);
          ao[j] = __builtin_fmaf(whj[6912 + k], hv, ao[j]);
        }
      }
    }

    float* __restrict__ hwp = &h_lds[1 - p][dir * 48 + ug * 12][0];
#pragma unroll
    for (int j = 0; j < 12; j++) {
      const float cc = sigm(af[j]) * c[j] + sigm(ai[j]) * tanh_f(ag[j]);
      c[j] = cc;
      hwp[j * 64 + lane] = sigm(ao[j]) * tanh_f(cc);
    }
    __syncthreads();
  }
  // final h (both dirs) is in h_lds[1]: rows 0..47 fw, 48..95 bw.
  // h_lds[0] is now free -> MLP scratch.

  // ---- MLP head, rows split across 8 waves; activations read LDS-direct ----
#pragma unroll 1
  for (int r = 0; r < 6; r++) {        // e1: 48 rows = 8 waves x 6
    asm volatile("" ::: "memory");
    const int rr = w * 6 + r;
    float a = e1b[rr];
#pragma unroll
    for (int k = 0; k < 96; k++) a = __builtin_fmaf(e1w[rr * 96 + k], h_lds[1][k][lane], a);
    h_lds[0][rr][lane] = a > 0.0f ? a : 0.0f;
  }
  __syncthreads();

  const int e2base = (w < 4) ? w * 5 : 20 + (w - 4) * 4;   // 36 rows: 5,5,5,5,4,4,4,4
  const int e2cnt  = (w < 4) ? 5 : 4;
#pragma unroll 1
  for (int r = 0; r < 5; r++) {
    asm volatile("" ::: "memory");
    if (r < e2cnt) {
      const int rr = e2base + r;
      float a = e2b[rr];
#pragma unroll
      for (int k = 0; k < 48; k++) a = __builtin_fmaf(e2w[rr * 48 + k], h_lds[0][k][lane], a);
      h_lds[0][48 + rr][lane] = a > 0.0f ? a : 0.0f;
    }
  }
  __syncthreads();

  if (w < 6) {                          // e3: 6 rows, one per wave
    float a = e3b[w];
#pragma unroll
    for (int k = 0; k < 36; k++) a = __builtin_fmaf(e3w[w * 36 + k], h_lds[0][48 + k][lane], a);
    out[(size_t)b * 6 + w] = a;
  }
}

extern "C" void kernel_launch(void* const* d_in, const int* in_sizes, int n_in,
                              void* d_out, int out_size, void* d_ws, size_t ws_size,
                              hipStream_t stream)
{
  const float* nf    = (const float*)d_in[0];
  const float* pos   = (const float*)d_in[1];
  const float* att   = (const float*)d_in[2];
  const float* msg_w = (const float*)d_in[3];
  const float* msg_b = (const float*)d_in[4];
  const float* gw_ih = (const float*)d_in[5];
  const float* gw_hh = (const float*)d_in[6];
  const float* gb_ih = (const float*)d_in[7];
  const float* gb_hh = (const float*)d_in[8];
  const float* wi_fw = (const float*)d_in[9];
  const float* wh_fw = (const float*)d_in[10];
  const float* bi_fw = (const float*)d_in[11];
  const float* bh_fw = (const float*)d_in[12];
  const float* wi_bw = (const float*)d_in[13];
  const float* wh_bw = (const float*)d_in[14];
  const float* bi_bw = (const float*)d_in[15];
  const float* bh_bw = (const float*)d_in[16];
  const float* e1w   = (const float*)d_in[17];
  const float* e1b   = (const float*)d_in[18];
  const float* e2w   = (const float*)d_in[19];
  const float* e2b   = (const float*)d_in[20];
  const float* e3w   = (const float*)d_in[21];
  const float* e3b   = (const float*)d_in[22];

  float* xt   = (float*)d_ws;   // [SL][48][NB] fp32 = 63 MB
  float* outp = (float*)d_out;

  msg_pass_kernel<<<(NB * SL * 4) / 256, 256, 0, stream>>>(
      nf, pos, att, msg_w, msg_b, gw_ih, gw_hh, gb_ih, gb_hh, xt);

  lstm_head_kernel<<<NB / 64, 512, 0, stream>>>(
      xt, wi_fw, wh_fw, bi_fw, bh_fw, wi_bw, wh_bw, bi_bw, bh_bw,
      e1w, e1b, e2w, e2b, e3w, e3b, outp);
}

// Round 6
// 356.826 us; speedup vs baseline: 4.5000x; 4.5000x over previous
//
#include <hip/hip_runtime.h>
#include <cstddef>

#define NB 65536
#define SL 5

typedef _Float16 f16;
typedef f16 half8 __attribute__((ext_vector_type(8)));
typedef float f32x4 __attribute__((ext_vector_type(4)));

__device__ __forceinline__ float sigm(float x)   { return 1.0f / (1.0f + __expf(-x)); }
__device__ __forceinline__ float tanh_f(float x) { return 2.0f / (1.0f + __expf(-2.0f * x)) - 1.0f; }

// ---------------------------------------------------------------------------
// prep: build f16 MFMA A-fragments for the LSTM weights + fused bias table.
// Fragment id fid = ((dir*4+ug)*3+mt)*3+kc. Per lane: 8 halfs, elem i holds
// W[row16 = lane&15 -> (unit u4 = r16>>2, gate g = r16&3)][k = kc*32+(lane>>4)*8+i]
// where unit j = ug*12 + mt*4 + u4, weight row = g*48 + j; k<48 -> w_ih, else w_hh.
// bsum[dir][ug][mt][r16] = b_ih[row] + b_hh[row].
// ---------------------------------------------------------------------------
__global__ __launch_bounds__(256) void prep_kernel(
    const float* __restrict__ wi_fw, const float* __restrict__ wh_fw,
    const float* __restrict__ bi_fw, const float* __restrict__ bh_fw,
    const float* __restrict__ wi_bw, const float* __restrict__ wh_bw,
    const float* __restrict__ bi_bw, const float* __restrict__ bh_bw,
    unsigned short* __restrict__ wfrag, float* __restrict__ bsum)
{
  const int t = blockIdx.x * 256 + threadIdx.x;
  if (t < 36864) {
    const int i = t & 7, lane = (t >> 3) & 63, fid = t >> 9;   // fid 0..71
    const int kc = fid % 3, mt = (fid / 3) % 3, ug = (fid / 9) & 3, dir = fid / 36;
    const int k = kc * 32 + (lane >> 4) * 8 + i;
    const int r16 = lane & 15;
    const int j = ug * 12 + mt * 4 + (r16 >> 2);
    const int g = r16 & 3;
    const float* wi = dir ? wi_bw : wi_fw;
    const float* wh = dir ? wh_bw : wh_fw;
    const float v = (k < 48) ? wi[(g * 48 + j) * 48 + k] : wh[(g * 48 + j) * 48 + (k - 48)];
    wfrag[t] = __builtin_bit_cast(unsigned short, (_Float16)v);
  } else if (t < 36864 + 384) {
    const int q = t - 36864;
    const int r16 = q & 15, mt = (q >> 4) % 3, ug = (q / 48) & 3, dir = q / 192;
    const int j = ug * 12 + mt * 4 + (r16 >> 2);
    const int g = r16 & 3;
    const int row = g * 48 + j;
    bsum[q] = dir ? (bi_bw[row] + bh_bw[row]) : (bi_fw[row] + bh_fw[row]);
  }
}

// ---------------------------------------------------------------------------
// Phase A: thread = (b, s, node); GRU in fp32 (unchanged structure from r4),
// but final store is f16 into xth[s][feat][b] (halves ws + feeds MFMA B path).
// ---------------------------------------------------------------------------
__global__ __launch_bounds__(256) void msg_pass_kernel(
    const float* __restrict__ nf, const float* __restrict__ pos,
    const float* __restrict__ att,
    const float* __restrict__ msg_w, const float* __restrict__ msg_b,
    const float* __restrict__ gw_ih, const float* __restrict__ gw_hh,
    const float* __restrict__ gb_ih, const float* __restrict__ gb_hh,
    unsigned short* __restrict__ xth)
{
  __shared__ float ma_lds[12][256];
  const int tid  = threadIdx.x;
  const int t    = blockIdx.x * 256 + tid;
  const int node = t & 3;
  const int rem  = t >> 2;            // = s*NB + b
  const int s    = rem >> 16;         // NB = 65536
  const int b    = rem & (NB - 1);
  const size_t ibase = ((size_t)(b * SL + s) * 4 + node) * 6;

  float h[12];
  {
    const float2* n2 = (const float2*)(nf  + ibase);
    const float2* p2 = (const float2*)(pos + ibase);
#pragma unroll
    for (int q = 0; q < 3; q++) {
      float2 v = n2[q]; h[q*2]   = v.x; h[q*2+1]   = v.y;
      float2 u = p2[q]; h[6+q*2] = u.x; h[6+q*2+1] = u.y;
    }
  }
  float ta[4];
  {
    float4 v = *(const float4*)(att + ((size_t)(b * SL + s) * 4 + node) * 4);
    ta[0] = v.x; ta[1] = v.y; ta[2] = v.z; ta[3] = v.w;
  }

#pragma unroll 1
  for (int pass = 0; pass < 2; ++pass) {
    if (pass) __syncthreads();
#pragma unroll
    for (int j = 0; j < 12; j++) {
      float a = msg_b[j];
#pragma unroll
      for (int i = 0; i < 12; i++) a = __builtin_fmaf(msg_w[j*12+i], h[i], a);
      ma_lds[j][tid] = a;
    }
    __syncthreads();
    const int base4 = tid & ~3;
    float mv[12];
#pragma unroll
    for (int j = 0; j < 12; j++) {
      mv[j] = ta[0]*ma_lds[j][base4]   + ta[1]*ma_lds[j][base4+1]
            + ta[2]*ma_lds[j][base4+2] + ta[3]*ma_lds[j][base4+3];
    }
    float hn[12];
#pragma unroll
    for (int j = 0; j < 12; j++) {
      float ar  = gb_ih[j]    + gb_hh[j];
      float az  = gb_ih[12+j] + gb_hh[12+j];
      float ani = gb_ih[24+j];
      float anh = gb_hh[24+j];
#pragma unroll
      for (int i = 0; i < 12; i++) {
        const float mvi = mv[i], hi = h[i];
        ar  = __builtin_fmaf(gw_ih[j*12+i],      mvi, ar);
        ar  = __builtin_fmaf(gw_hh[j*12+i],      hi,  ar);
        az  = __builtin_fmaf(gw_ih[(12+j)*12+i], mvi, az);
        az  = __builtin_fmaf(gw_hh[(12+j)*12+i], hi,  az);
        ani = __builtin_fmaf(gw_ih[(24+j)*12+i], mvi, ani);
        anh = __builtin_fmaf(gw_hh[(24+j)*12+i], hi,  anh);
      }
      const float r = sigm(ar), z = sigm(az);
      const float g = tanh_f(ani + r * anh);
      hn[j] = (1.0f - z) * g + z * h[j];
    }
#pragma unroll
    for (int j = 0; j < 12; j++) h[j] = hn[j];
  }

#pragma unroll
  for (int d = 0; d < 12; d++)
    xth[(size_t)(s * 48 + d * 4 + node) * NB + b] =
        __builtin_bit_cast(unsigned short, (_Float16)h[d]);
}

// ---------------------------------------------------------------------------
// Phase B+C: biLSTM via MFMA (f16 in / f32 accum) + MLP head.
// Block = 512 thr (8 waves) x 64 batches. Wave = (dir = w&1, ug = w>>1):
// computes 48 gate-rows (12 units x 4 gates) x 64 batches per step.
// Weights: 9 A-frags (36 VGPR) loaded ONCE - zero per-step weight traffic.
// Activations: f16 LDS act[dir][n][104] (k 0..47 = x, 48..95 = h),
// single-buffered, 2 barriers/step. C layout (m89-verified): lane ->
// (col = batch = lane&15, rows = unit (lane>>4), regs = gates i,f,g,o).
// ---------------------------------------------------------------------------
__global__ __launch_bounds__(512) void lstm_mfma_kernel(
    const unsigned short* __restrict__ xth,
    const unsigned short* __restrict__ wfrag,
    const float* __restrict__ bsum,
    const float* __restrict__ e1w, const float* __restrict__ e1b,
    const float* __restrict__ e2w, const float* __restrict__ e2b,
    const float* __restrict__ e3w, const float* __restrict__ e3b,
    float* __restrict__ out)
{
  __shared__ unsigned short act[2][64][104];   // f16 bits; stride 104 halfs (16B-aligned rows)
  __shared__ float mlp1[48][65];
  __shared__ float mlp2[36][65];

  const int tid  = threadIdx.x;
  const int lane = tid & 63;
  const int w    = __builtin_amdgcn_readfirstlane(tid >> 6);  // wave 0..7
  const int dir  = w & 1;
  const int ug   = w >> 1;
  const int b0   = blockIdx.x * 64;
  const int col  = lane & 15;
  const int grp  = lane >> 4;

  // --- load A-frags (held in VGPRs for the entire kernel) + bias ---
  half8 A[3][3];
#pragma unroll
  for (int mt = 0; mt < 3; ++mt)
#pragma unroll
    for (int kc = 0; kc < 3; ++kc) {
      const int fid = ((dir * 4 + ug) * 3 + mt) * 3 + kc;
      A[mt][kc] = *reinterpret_cast<const half8*>(wfrag + (size_t)(fid * 64 + lane) * 8);
    }
  f32x4 bias[3];
#pragma unroll
  for (int mt = 0; mt < 3; ++mt)
    bias[mt] = *reinterpret_cast<const f32x4*>(bsum + ((dir * 4 + ug) * 3 + mt) * 16 + grp * 4);

  // --- prologue: x(step0) for both dirs; zero h region ---
#pragma unroll
  for (int ff = 0; ff < 6; ++ff) {
    const int f = w * 6 + ff;
    act[0][lane][f] = xth[(size_t)(0 * 48 + f) * NB + b0 + lane];
    act[1][lane][f] = xth[(size_t)(4 * 48 + f) * NB + b0 + lane];
  }
#pragma unroll
  for (int jj = 0; jj < 12; ++jj)
    act[dir][lane][48 + ug * 12 + jj] = 0;
  __syncthreads();

  float c[3][4];
#pragma unroll
  for (int mt = 0; mt < 3; ++mt)
#pragma unroll
    for (int nt = 0; nt < 4; ++nt) c[mt][nt] = 0.0f;
  unsigned short hst[3][4];

#pragma unroll 1
  for (int st = 0; st < 5; ++st) {
#pragma unroll
    for (int nt = 0; nt < 4; ++nt) {
      const int n = nt * 16 + col;
      half8 B0 = *reinterpret_cast<const half8*>(&act[dir][n][grp * 8]);
      half8 B1 = *reinterpret_cast<const half8*>(&act[dir][n][32 + grp * 8]);
      half8 B2 = *reinterpret_cast<const half8*>(&act[dir][n][64 + grp * 8]);
      f32x4 C0 = bias[0], C1 = bias[1], C2 = bias[2];
      C0 = __builtin_amdgcn_mfma_f32_16x16x32_f16(A[0][0], B0, C0, 0, 0, 0);
      C0 = __builtin_amdgcn_mfma_f32_16x16x32_f16(A[0][1], B1, C0, 0, 0, 0);
      C0 = __builtin_amdgcn_mfma_f32_16x16x32_f16(A[0][2], B2, C0, 0, 0, 0);
      C1 = __builtin_amdgcn_mfma_f32_16x16x32_f16(A[1][0], B0, C1, 0, 0, 0);
      C1 = __builtin_amdgcn_mfma_f32_16x16x32_f16(A[1][1], B1, C1, 0, 0, 0);
      C1 = __builtin_amdgcn_mfma_f32_16x16x32_f16(A[1][2], B2, C1, 0, 0, 0);
      C2 = __builtin_amdgcn_mfma_f32_16x16x32_f16(A[2][0], B0, C2, 0, 0, 0);
      C2 = __builtin_amdgcn_mfma_f32_16x16x32_f16(A[2][1], B1, C2, 0, 0, 0);
      C2 = __builtin_amdgcn_mfma_f32_16x16x32_f16(A[2][2], B2, C2, 0, 0, 0);
      // epilogue: regs = gates i,f,g,o of unit (mt, grp), col = batch n
#pragma unroll
      for (int mt = 0; mt < 3; ++mt) {
        const f32x4 C = (mt == 0) ? C0 : (mt == 1) ? C1 : C2;
        const float cc = sigm(C[1]) * c[mt][nt] + sigm(C[0]) * tanh_f(C[2]);
        c[mt][nt] = cc;
        const float hv = sigm(C[3]) * tanh_f(cc);
        hst[mt][nt] = __builtin_bit_cast(unsigned short, (_Float16)hv);
      }
    }
    __syncthreads();                       // all act reads complete
    // write h(t+1) for own (dir, units)
#pragma unroll
    for (int mt = 0; mt < 3; ++mt)
#pragma unroll
      for (int nt = 0; nt < 4; ++nt)
        act[dir][nt * 16 + col][48 + ug * 12 + mt * 4 + grp] = hst[mt][nt];
    // stream next step's x (fw: s+1, bw: 3-st)
    if (st < 4) {
      const int s0 = st + 1, s1 = 3 - st;
#pragma unroll
      for (int ff = 0; ff < 6; ++ff) {
        const int f = w * 6 + ff;
        act[0][lane][f] = xth[(size_t)(s0 * 48 + f) * NB + b0 + lane];
        act[1][lane][f] = xth[(size_t)(s1 * 48 + f) * NB + b0 + lane];
      }
    }
    __syncthreads();
  }
  // final h: act[0][n][48..95] = fw, act[1][n][48..95] = bw

  // ---- MLP head: rows split across 8 waves ----
#pragma unroll 1
  for (int r = 0; r < 6; ++r) {            // e1: 48 rows = 8 waves x 6
    const int rr = w * 6 + r;
    float a = e1b[rr];
#pragma unroll
    for (int k = 0; k < 48; ++k)
      a = __builtin_fmaf(e1w[rr * 96 + k],
                         (float)__builtin_bit_cast(_Float16, act[0][lane][48 + k]), a);
#pragma unroll
    for (int k = 0; k < 48; ++k)
      a = __builtin_fmaf(e1w[rr * 96 + 48 + k],
                         (float)__builtin_bit_cast(_Float16, act[1][lane][48 + k]), a);
    mlp1[rr][lane] = a > 0.0f ? a : 0.0f;
  }
  __syncthreads();

  const int e2base = (w < 4) ? w * 5 : 20 + (w - 4) * 4;   // 36 rows: 5,5,5,5,4,4,4,4
  const int e2cnt  = (w < 4) ? 5 : 4;
#pragma unroll 1
  for (int r = 0; r < 5; ++r) {
    if (r < e2cnt) {
      const int rr = e2base + r;
      float a = e2b[rr];
#pragma unroll
      for (int k = 0; k < 48; ++k) a = __builtin_fmaf(e2w[rr * 48 + k], mlp1[k][lane], a);
      mlp2[rr][lane] = a > 0.0f ? a : 0.0f;
    }
  }
  __syncthreads();

  if (w < 6) {                              // e3: 6 rows, one per wave
    float a = e3b[w];
#pragma unroll
    for (int k = 0; k < 36; ++k) a = __builtin_fmaf(e3w[w * 36 + k], mlp2[k][lane], a);
    out[(size_t)(b0 + lane) * 6 + w] = a;
  }
}

extern "C" void kernel_launch(void* const* d_in, const int* in_sizes, int n_in,
                              void* d_out, int out_size, void* d_ws, size_t ws_size,
                              hipStream_t stream)
{
  const float* nf    = (const float*)d_in[0];
  const float* pos   = (const float*)d_in[1];
  const float* att   = (const float*)d_in[2];
  const float* msg_w = (const float*)d_in[3];
  const float* msg_b = (const float*)d_in[4];
  const float* gw_ih = (const float*)d_in[5];
  const float* gw_hh = (const float*)d_in[6];
  const float* gb_ih = (const float*)d_in[7];
  const float* gb_hh = (const float*)d_in[8];
  const float* wi_fw = (const float*)d_in[9];
  const float* wh_fw = (const float*)d_in[10];
  const float* bi_fw = (const float*)d_in[11];
  const float* bh_fw = (const float*)d_in[12];
  const float* wi_bw = (const float*)d_in[13];
  const float* wh_bw = (const float*)d_in[14];
  const float* bi_bw = (const float*)d_in[15];
  const float* bh_bw = (const float*)d_in[16];
  const float* e1w   = (const float*)d_in[17];
  const float* e1b   = (const float*)d_in[18];
  const float* e2w   = (const float*)d_in[19];
  const float* e2b   = (const float*)d_in[20];
  const float* e3w   = (const float*)d_in[21];
  const float* e3b   = (const float*)d_in[22];

  // ws layout: xth [SL][48][NB] f16 (31.5MB) | wfrag 36864 u16 | bsum 384 f32
  unsigned short* xth   = (unsigned short*)d_ws;
  unsigned short* wfrag = xth + (size_t)SL * 48 * NB;
  float*          bsum  = (float*)(wfrag + 36864);
  float*          outp  = (float*)d_out;

  prep_kernel<<<146, 256, 0, stream>>>(
      wi_fw, wh_fw, bi_fw, bh_fw, wi_bw, wh_bw, bi_bw, bh_bw, wfrag, bsum);

  msg_pass_kernel<<<(NB * SL * 4) / 256, 256, 0, stream>>>(
      nf, pos, att, msg_w, msg_b, gw_ih, gw_hh, gb_ih, gb_hh, xth);

  lstm_mfma_kernel<<<NB / 64, 512, 0, stream>>>(
      xth, wfrag, bsum, e1w, e1b, e2w, e2b, e3w, e3b, outp);
}

// Round 7
// 213.103 us; speedup vs baseline: 7.5349x; 1.6744x over previous
//
#include <hip/hip_runtime.h>
#include <cstddef>

#define NB 65536
#define SL 5

typedef _Float16 f16;
typedef f16 half8 __attribute__((ext_vector_type(8)));
typedef float f32x4 __attribute__((ext_vector_type(4)));

__device__ __forceinline__ float sigm(float x)   { return 1.0f / (1.0f + __expf(-x)); }
__device__ __forceinline__ float tanh_f(float x) { return 2.0f / (1.0f + __expf(-2.0f * x)) - 1.0f; }

// ---------------------------------------------------------------------------
// prep: f16 MFMA A-fragments.
// LSTM (unchanged from r6): wfrag fid = ((dir*4+ug)*3+mt)*3+kc; bsum.
// GRU (new): mfrag fid 0 = GEMM1 A (msg_w at rows<12, k=12..23);
// fid 1..3 = GEMM2 M-tiles: rows R=(fid-1)*16+r16, R=kind*12+j:
//   kind0: r-gate [gw_ih_r | gw_hh_r]; kind1: z-gate; kind2: n_ih; kind3: n_hh.
// mbias: [0..15] = msg_b (pad 0); [16..63] = GEMM2 row biases.
// ---------------------------------------------------------------------------
__global__ __launch_bounds__(256) void prep_kernel(
    const float* __restrict__ wi_fw, const float* __restrict__ wh_fw,
    const float* __restrict__ bi_fw, const float* __restrict__ bh_fw,
    const float* __restrict__ wi_bw, const float* __restrict__ wh_bw,
    const float* __restrict__ bi_bw, const float* __restrict__ bh_bw,
    const float* __restrict__ msg_w, const float* __restrict__ msg_b,
    const float* __restrict__ gw_ih, const float* __restrict__ gw_hh,
    const float* __restrict__ gb_ih, const float* __restrict__ gb_hh,
    unsigned short* __restrict__ wfrag, float* __restrict__ bsum,
    unsigned short* __restrict__ mfrag, float* __restrict__ mbias)
{
  const int t = blockIdx.x * 256 + threadIdx.x;
  if (t < 36864) {
    const int i = t & 7, lane = (t >> 3) & 63, fid = t >> 9;   // fid 0..71
    const int kc = fid % 3, mt = (fid / 3) % 3, ug = (fid / 9) & 3, dir = fid / 36;
    const int k = kc * 32 + (lane >> 4) * 8 + i;
    const int r16 = lane & 15;
    const int j = ug * 12 + mt * 4 + (r16 >> 2);
    const int g = r16 & 3;
    const float* wi = dir ? wi_bw : wi_fw;
    const float* wh = dir ? wh_bw : wh_fw;
    const float v = (k < 48) ? wi[(g * 48 + j) * 48 + k] : wh[(g * 48 + j) * 48 + (k - 48)];
    wfrag[t] = __builtin_bit_cast(unsigned short, (_Float16)v);
  } else if (t < 37248) {
    const int q = t - 36864;
    const int r16 = q & 15, mt = (q >> 4) % 3, ug = (q / 48) & 3, dir = q / 192;
    const int j = ug * 12 + mt * 4 + (r16 >> 2);
    const int g = r16 & 3;
    const int row = g * 48 + j;
    bsum[q] = dir ? (bi_bw[row] + bh_bw[row]) : (bi_fw[row] + bh_fw[row]);
  } else if (t < 39296) {
    const int q = t - 37248;
    const int i = q & 7, lane = (q >> 3) & 63, fid = q >> 9;   // 0..3
    const int k = ((lane >> 4) << 3) + i;                      // 0..31
    const int r16 = lane & 15;
    float v = 0.0f;
    if (fid == 0) {
      if (r16 < 12 && k >= 12 && k < 24) v = msg_w[r16 * 12 + (k - 12)];
    } else {
      const int R = (fid - 1) * 16 + r16;                      // 0..47
      const int kind = R / 12, j = R % 12;
      if (kind == 0)      v = (k < 12) ? gw_ih[j * 12 + k]          : ((k < 24) ? gw_hh[j * 12 + (k - 12)] : 0.0f);
      else if (kind == 1) v = (k < 12) ? gw_ih[(12 + j) * 12 + k]   : ((k < 24) ? gw_hh[(12 + j) * 12 + (k - 12)] : 0.0f);
      else if (kind == 2) v = (k < 12) ? gw_ih[(24 + j) * 12 + k]   : 0.0f;
      else                v = (k >= 12 && k < 24) ? gw_hh[(24 + j) * 12 + (k - 12)] : 0.0f;
    }
    mfrag[q] = __builtin_bit_cast(unsigned short, (_Float16)v);
  } else if (t < 39360) {
    const int q = t - 39296;
    if (q < 16) mbias[q] = (q < 12) ? msg_b[q] : 0.0f;
    else {
      const int R = q - 16, kind = R / 12, j = R % 12;
      float v;
      if (kind == 0)      v = gb_ih[j] + gb_hh[j];
      else if (kind == 1) v = gb_ih[12 + j] + gb_hh[12 + j];
      else if (kind == 2) v = gb_ih[24 + j];
      else                v = gb_hh[24 + j];
      mbias[q] = v;
    }
  }
}

// ---------------------------------------------------------------------------
// Phase A via MFMA. Block = 256 thr (4 waves) = 256 columns = 64 samples x 4
// nodes. Column c (= tid): sample_local = (c>>6)*16 + ((c>>4)&3)*4 + ((c>>2)&3),
// node = c&3. Tile cols (16) = 4 samples x 4 nodes; wave owns 4 tiles.
// Per pass: GEMM1 (1 MFMA/tile) -> m_all f16 in g_lds -> per-lane attention
// mix (f32) -> mv f16 to B_lds -> GEMM2 (3 MFMA/tile) -> gates f16 in g_lds
// -> per-lane GRU (h kept f32 in regs). B_lds[col][k]: 0..11 mv, 12..23 h,
// 24..31 zero. Row pads (40/50 halfs) kill bank conflicts.
// ---------------------------------------------------------------------------
__global__ __launch_bounds__(256) void msg_mfma_kernel(
    const float* __restrict__ nf, const float* __restrict__ pos,
    const float* __restrict__ att,
    const unsigned short* __restrict__ mfrag, const float* __restrict__ mbias,
    unsigned short* __restrict__ xth)
{
  __shared__ unsigned short B_lds[256][40];   // f16 bits, 80B rows
  __shared__ unsigned short g_lds[256][50];   // f16 bits, 100B rows

  const int tid  = threadIdx.x;
  const int lane = tid & 63;
  const int w    = __builtin_amdgcn_readfirstlane(tid >> 6);
  const int c16  = lane & 15;
  const int grp  = lane >> 4;
  const int own  = tid;                       // own column
  const int node = own & 3;
  const int sl   = (own >> 6) * 16 + ((own >> 4) & 3) * 4 + ((own >> 2) & 3);

  // A-fragments + biases (pinned in VGPRs for the whole kernel)
  half8 A1 = *reinterpret_cast<const half8*>(mfrag + (size_t)lane * 8);
  half8 A2[3];
#pragma unroll
  for (int mt = 0; mt < 3; ++mt)
    A2[mt] = *reinterpret_cast<const half8*>(mfrag + (size_t)((1 + mt) * 64 + lane) * 8);
  const f32x4 bias1 = *reinterpret_cast<const f32x4*>(mbias + grp * 4);
  f32x4 bias2[3];
#pragma unroll
  for (int mt = 0; mt < 3; ++mt)
    bias2[mt] = *reinterpret_cast<const f32x4*>(mbias + 16 + mt * 16 + grp * 4);

  // zero B_lds (covers the k=24..31 pad and initial mv slots)
  {
    unsigned int* bz = reinterpret_cast<unsigned int*>(&B_lds[0][0]);
#pragma unroll
    for (int q = 0; q < 20; ++q) bz[tid * 20 + q] = 0u;
  }

  // h0 = concat(nf, pos) for own column; f32 in regs across passes
  const int sid = blockIdx.x * 64 + sl;
  const int s   = sid >> 16;
  const int b   = sid & (NB - 1);
  float h[12];
  {
    const size_t ib = ((size_t)(b * SL + s) * 4 + node) * 6;
    const float2* n2 = (const float2*)(nf  + ib);
    const float2* p2 = (const float2*)(pos + ib);
#pragma unroll
    for (int q = 0; q < 3; q++) {
      float2 v = n2[q]; h[q*2]   = v.x; h[q*2+1]   = v.y;
      float2 u = p2[q]; h[6+q*2] = u.x; h[6+q*2+1] = u.y;
    }
  }
  float ta[4];
  {
    float4 v = *(const float4*)(att + ((size_t)(b * SL + s) * 4 + node) * 4);
    ta[0] = v.x; ta[1] = v.y; ta[2] = v.z; ta[3] = v.w;
  }
#pragma unroll
  for (int d = 0; d < 12; ++d)
    B_lds[own][12 + d] = __builtin_bit_cast(unsigned short, (_Float16)h[d]);
  __syncthreads();

#pragma unroll 1
  for (int pass = 0; pass < 2; ++pass) {
    // --- GEMM1: m_all (rows 0..11) ---
#pragma unroll
    for (int nt = 0; nt < 4; ++nt) {
      const int col = w * 64 + nt * 16 + c16;
      half8 B = *reinterpret_cast<const half8*>(&B_lds[col][grp * 8]);
      f32x4 C = __builtin_amdgcn_mfma_f32_16x16x32_f16(A1, B, bias1, 0, 0, 0);
      if (grp < 3) {
#pragma unroll
        for (int r = 0; r < 4; ++r)
          g_lds[col][grp * 4 + r] = __builtin_bit_cast(unsigned short, (_Float16)C[r]);
      }
    }
    __syncthreads();

    // --- attention mix (per own column, f32) ---
    {
      const int cb = own & ~3;
      float mv[12];
#pragma unroll
      for (int d = 0; d < 12; ++d) mv[d] = 0.0f;
#pragma unroll
      for (int ww = 0; ww < 4; ++ww) {
        const float a = ta[ww];
#pragma unroll
        for (int d = 0; d < 12; ++d) {
          const float m = (float)__builtin_bit_cast(_Float16, g_lds[cb + ww][d]);
          mv[d] = __builtin_fmaf(a, m, mv[d]);
        }
      }
#pragma unroll
      for (int d = 0; d < 12; ++d)
        B_lds[own][d] = __builtin_bit_cast(unsigned short, (_Float16)mv[d]);
    }
    __syncthreads();

    // --- GEMM2: gates, 48 rows = [r | z | n_ih | n_hh] ---
#pragma unroll
    for (int nt = 0; nt < 4; ++nt) {
      const int col = w * 64 + nt * 16 + c16;
      half8 B = *reinterpret_cast<const half8*>(&B_lds[col][grp * 8]);
      f32x4 C0 = __builtin_amdgcn_mfma_f32_16x16x32_f16(A2[0], B, bias2[0], 0, 0, 0);
      f32x4 C1 = __builtin_amdgcn_mfma_f32_16x16x32_f16(A2[1], B, bias2[1], 0, 0, 0);
      f32x4 C2 = __builtin_amdgcn_mfma_f32_16x16x32_f16(A2[2], B, bias2[2], 0, 0, 0);
#pragma unroll
      for (int r = 0; r < 4; ++r) {
        g_lds[col][grp * 4 + r]      = __builtin_bit_cast(unsigned short, (_Float16)C0[r]);
        g_lds[col][16 + grp * 4 + r] = __builtin_bit_cast(unsigned short, (_Float16)C1[r]);
        g_lds[col][32 + grp * 4 + r] = __builtin_bit_cast(unsigned short, (_Float16)C2[r]);
      }
    }
    __syncthreads();

    // --- GRU update (per own column; h stays f32) ---
#pragma unroll
    for (int j = 0; j < 12; ++j) {
      const float Gr = (float)__builtin_bit_cast(_Float16, g_lds[own][j]);
      const float Gz = (float)__builtin_bit_cast(_Float16, g_lds[own][12 + j]);
      const float Gi = (float)__builtin_bit_cast(_Float16, g_lds[own][24 + j]);
      const float Gh = (float)__builtin_bit_cast(_Float16, g_lds[own][36 + j]);
      const float r = sigm(Gr), z = sigm(Gz);
      const float g = tanh_f(Gi + r * Gh);
      h[j] = (1.0f - z) * g + z * h[j];
    }
#pragma unroll
    for (int d = 0; d < 12; ++d)
      B_lds[own][12 + d] = __builtin_bit_cast(unsigned short, (_Float16)h[d]);
    __syncthreads();
  }

  // --- store: xth[(s*48+f)*NB + b], coalesced via LDS transpose ---
  const int b0 = (blockIdx.x * 64) & (NB - 1);
#pragma unroll
  for (int ff = 0; ff < 12; ++ff) {
    const int f  = w * 12 + ff;
    const int d  = f >> 2, nd = f & 3;
    const int i  = lane;                                   // batch offset
    const int cg = (i >> 4) * 64 + ((i >> 2) & 3) * 16 + (i & 3) * 4 + nd;
    xth[(size_t)(s * 48 + f) * NB + b0 + i] = B_lds[cg][12 + d];
  }
}

// ---------------------------------------------------------------------------
// Phase B+C: biLSTM via MFMA + MLP head (unchanged from round 6).
// ---------------------------------------------------------------------------
__global__ __launch_bounds__(512) void lstm_mfma_kernel(
    const unsigned short* __restrict__ xth,
    const unsigned short* __restrict__ wfrag,
    const float* __restrict__ bsum,
    const float* __restrict__ e1w, const float* __restrict__ e1b,
    const float* __restrict__ e2w, const float* __restrict__ e2b,
    const float* __restrict__ e3w, const float* __restrict__ e3b,
    float* __restrict__ out)
{
  __shared__ unsigned short act[2][64][104];
  __shared__ float mlp1[48][65];
  __shared__ float mlp2[36][65];

  const int tid  = threadIdx.x;
  const int lane = tid & 63;
  const int w    = __builtin_amdgcn_readfirstlane(tid >> 6);
  const int dir  = w & 1;
  const int ug   = w >> 1;
  const int b0   = blockIdx.x * 64;
  const int col  = lane & 15;
  const int grp  = lane >> 4;

  half8 A[3][3];
#pragma unroll
  for (int mt = 0; mt < 3; ++mt)
#pragma unroll
    for (int kc = 0; kc < 3; ++kc) {
      const int fid = ((dir * 4 + ug) * 3 + mt) * 3 + kc;
      A[mt][kc] = *reinterpret_cast<const half8*>(wfrag + (size_t)(fid * 64 + lane) * 8);
    }
  f32x4 bias[3];
#pragma unroll
  for (int mt = 0; mt < 3; ++mt)
    bias[mt] = *reinterpret_cast<const f32x4*>(bsum + ((dir * 4 + ug) * 3 + mt) * 16 + grp * 4);

#pragma unroll
  for (int ff = 0; ff < 6; ++ff) {
    const int f = w * 6 + ff;
    act[0][lane][f] = xth[(size_t)(0 * 48 + f) * NB + b0 + lane];
    act[1][lane][f] = xth[(size_t)(4 * 48 + f) * NB + b0 + lane];
  }
#pragma unroll
  for (int jj = 0; jj < 12; ++jj)
    act[dir][lane][48 + ug * 12 + jj] = 0;
  __syncthreads();

  float c[3][4];
#pragma unroll
  for (int mt = 0; mt < 3; ++mt)
#pragma unroll
    for (int nt = 0; nt < 4; ++nt) c[mt][nt] = 0.0f;
  unsigned short hst[3][4];

#pragma unroll 1
  for (int st = 0; st < 5; ++st) {
#pragma unroll
    for (int nt = 0; nt < 4; ++nt) {
      const int n = nt * 16 + col;
      half8 B0 = *reinterpret_cast<const half8*>(&act[dir][n][grp * 8]);
      half8 B1 = *reinterpret_cast<const half8*>(&act[dir][n][32 + grp * 8]);
      half8 B2 = *reinterpret_cast<const half8*>(&act[dir][n][64 + grp * 8]);
      f32x4 C0 = bias[0], C1 = bias[1], C2 = bias[2];
      C0 = __builtin_amdgcn_mfma_f32_16x16x32_f16(A[0][0], B0, C0, 0, 0, 0);
      C0 = __builtin_amdgcn_mfma_f32_16x16x32_f16(A[0][1], B1, C0, 0, 0, 0);
      C0 = __builtin_amdgcn_mfma_f32_16x16x32_f16(A[0][2], B2, C0, 0, 0, 0);
      C1 = __builtin_amdgcn_mfma_f32_16x16x32_f16(A[1][0], B0, C1, 0, 0, 0);
      C1 = __builtin_amdgcn_mfma_f32_16x16x32_f16(A[1][1], B1, C1, 0, 0, 0);
      C1 = __builtin_amdgcn_mfma_f32_16x16x32_f16(A[1][2], B2, C1, 0, 0, 0);
      C2 = __builtin_amdgcn_mfma_f32_16x16x32_f16(A[2][0], B0, C2, 0, 0, 0);
      C2 = __builtin_amdgcn_mfma_f32_16x16x32_f16(A[2][1], B1, C2, 0, 0, 0);
      C2 = __builtin_amdgcn_mfma_f32_16x16x32_f16(A[2][2], B2, C2, 0, 0, 0);
#pragma unroll
      for (int mt = 0; mt < 3; ++mt) {
        const f32x4 C = (mt == 0) ? C0 : (mt == 1) ? C1 : C2;
        const float cc = sigm(C[1]) * c[mt][nt] + sigm(C[0]) * tanh_f(C[2]);
        c[mt][nt] = cc;
        const float hv = sigm(C[3]) * tanh_f(cc);
        hst[mt][nt] = __builtin_bit_cast(unsigned short, (_Float16)hv);
      }
    }
    __syncthreads();
#pragma unroll
    for (int mt = 0; mt < 3; ++mt)
#pragma unroll
      for (int nt = 0; nt < 4; ++nt)
        act[dir][nt * 16 + col][48 + ug * 12 + mt * 4 + grp] = hst[mt][nt];
    if (st < 4) {
      const int s0 = st + 1, s1 = 3 - st;
#pragma unroll
      for (int ff = 0; ff < 6; ++ff) {
        const int f = w * 6 + ff;
        act[0][lane][f] = xth[(size_t)(s0 * 48 + f) * NB + b0 + lane];
        act[1][lane][f] = xth[(size_t)(s1 * 48 + f) * NB + b0 + lane];
      }
    }
    __syncthreads();
  }

#pragma unroll 1
  for (int r = 0; r < 6; ++r) {
    const int rr = w * 6 + r;
    float a = e1b[rr];
#pragma unroll
    for (int k = 0; k < 48; ++k)
      a = __builtin_fmaf(e1w[rr * 96 + k],
                         (float)__builtin_bit_cast(_Float16, act[0][lane][48 + k]), a);
#pragma unroll
    for (int k = 0; k < 48; ++k)
      a = __builtin_fmaf(e1w[rr * 96 + 48 + k],
                         (float)__builtin_bit_cast(_Float16, act[1][lane][48 + k]), a);
    mlp1[rr][lane] = a > 0.0f ? a : 0.0f;
  }
  __syncthreads();

  const int e2base = (w < 4) ? w * 5 : 20 + (w - 4) * 4;
  const int e2cnt  = (w < 4) ? 5 : 4;
#pragma unroll 1
  for (int r = 0; r < 5; ++r) {
    if (r < e2cnt) {
      const int rr = e2base + r;
      float a = e2b[rr];
#pragma unroll
      for (int k = 0; k < 48; ++k) a = __builtin_fmaf(e2w[rr * 48 + k], mlp1[k][lane], a);
      mlp2[rr][lane] = a > 0.0f ? a : 0.0f;
    }
  }
  __syncthreads();

  if (w < 6) {
    float a = e3b[w];
#pragma unroll
    for (int k = 0; k < 36; ++k) a = __builtin_fmaf(e3w[w * 36 + k], mlp2[k][lane], a);
    out[(size_t)(b0 + lane) * 6 + w] = a;
  }
}

extern "C" void kernel_launch(void* const* d_in, const int* in_sizes, int n_in,
                              void* d_out, int out_size, void* d_ws, size_t ws_size,
                              hipStream_t stream)
{
  const float* nf    = (const float*)d_in[0];
  const float* pos   = (const float*)d_in[1];
  const float* att   = (const float*)d_in[2];
  const float* msg_w = (const float*)d_in[3];
  const float* msg_b = (const float*)d_in[4];
  const float* gw_ih = (const float*)d_in[5];
  const float* gw_hh = (const float*)d_in[6];
  const float* gb_ih = (const float*)d_in[7];
  const float* gb_hh = (const float*)d_in[8];
  const float* wi_fw = (const float*)d_in[9];
  const float* wh_fw = (const float*)d_in[10];
  const float* bi_fw = (const float*)d_in[11];
  const float* bh_fw = (const float*)d_in[12];
  const float* wi_bw = (const float*)d_in[13];
  const float* wh_bw = (const float*)d_in[14];
  const float* bi_bw = (const float*)d_in[15];
  const float* bh_bw = (const float*)d_in[16];
  const float* e1w   = (const float*)d_in[17];
  const float* e1b   = (const float*)d_in[18];
  const float* e2w   = (const float*)d_in[19];
  const float* e2b   = (const float*)d_in[20];
  const float* e3w   = (const float*)d_in[21];
  const float* e3b   = (const float*)d_in[22];

  // ws: xth [SL][48][NB] f16 | wfrag 36864 u16 | bsum 384 f32 | mfrag 2048 u16 | mbias 64 f32
  unsigned short* xth   = (unsigned short*)d_ws;
  unsigned short* wfrag = xth + (size_t)SL * 48 * NB;
  float*          bsum  = (float*)(wfrag + 36864);
  unsigned short* mfrag = (unsigned short*)(bsum + 384);
  float*          mbias = (float*)(mfrag + 2048);
  float*          outp  = (float*)d_out;

  prep_kernel<<<154, 256, 0, stream>>>(
      wi_fw, wh_fw, bi_fw, bh_fw, wi_bw, wh_bw, bi_bw, bh_bw,
      msg_w, msg_b, gw_ih, gw_hh, gb_ih, gb_hh,
      wfrag, bsum, mfrag, mbias);

  msg_mfma_kernel<<<(NB * SL) / 64, 256, 0, stream>>>(
      nf, pos, att, mfrag, mbias, xth);

  lstm_mfma_kernel<<<NB / 64, 512, 0, stream>>>(
      xth, wfrag, bsum, e1w, e1b, e2w, e2b, e3w, e3b, outp);
}

// Round 8
// 185.748 us; speedup vs baseline: 8.6446x; 1.1473x over previous
//
#include <hip/hip_runtime.h>
#include <cstddef>

#define NB 65536
#define SL 5

typedef _Float16 f16;
typedef f16 half8 __attribute__((ext_vector_type(8)));
typedef float f32x4 __attribute__((ext_vector_type(4)));

__device__ __forceinline__ float sigm(float x)   { return 1.0f / (1.0f + __expf(-x)); }
__device__ __forceinline__ float tanh_f(float x) { return 2.0f / (1.0f + __expf(-2.0f * x)) - 1.0f; }
__device__ __forceinline__ unsigned int pkh2(float a, float b) {
  return (unsigned int)__builtin_bit_cast(unsigned short, (_Float16)a)
       | ((unsigned int)__builtin_bit_cast(unsigned short, (_Float16)b) << 16);
}
__device__ __forceinline__ float loh(unsigned int u) {
  return (float)__builtin_bit_cast(_Float16, (unsigned short)(u & 0xffffu));
}
__device__ __forceinline__ float hih(unsigned int u) {
  return (float)__builtin_bit_cast(_Float16, (unsigned short)(u >> 16));
}

// ---------------------------------------------------------------------------
// prep: f16 MFMA A-fragments (unchanged from round 7).
// ---------------------------------------------------------------------------
__global__ __launch_bounds__(256) void prep_kernel(
    const float* __restrict__ wi_fw, const float* __restrict__ wh_fw,
    const float* __restrict__ bi_fw, const float* __restrict__ bh_fw,
    const float* __restrict__ wi_bw, const float* __restrict__ wh_bw,
    const float* __restrict__ bi_bw, const float* __restrict__ bh_bw,
    const float* __restrict__ msg_w, const float* __restrict__ msg_b,
    const float* __restrict__ gw_ih, const float* __restrict__ gw_hh,
    const float* __restrict__ gb_ih, const float* __restrict__ gb_hh,
    unsigned short* __restrict__ wfrag, float* __restrict__ bsum,
    unsigned short* __restrict__ mfrag, float* __restrict__ mbias)
{
  const int t = blockIdx.x * 256 + threadIdx.x;
  if (t < 36864) {
    const int i = t & 7, lane = (t >> 3) & 63, fid = t >> 9;
    const int kc = fid % 3, mt = (fid / 3) % 3, ug = (fid / 9) & 3, dir = fid / 36;
    const int k = kc * 32 + (lane >> 4) * 8 + i;
    const int r16 = lane & 15;
    const int j = ug * 12 + mt * 4 + (r16 >> 2);
    const int g = r16 & 3;
    const float* wi = dir ? wi_bw : wi_fw;
    const float* wh = dir ? wh_bw : wh_fw;
    const float v = (k < 48) ? wi[(g * 48 + j) * 48 + k] : wh[(g * 48 + j) * 48 + (k - 48)];
    wfrag[t] = __builtin_bit_cast(unsigned short, (_Float16)v);
  } else if (t < 37248) {
    const int q = t - 36864;
    const int r16 = q & 15, mt = (q >> 4) % 3, ug = (q / 48) & 3, dir = q / 192;
    const int j = ug * 12 + mt * 4 + (r16 >> 2);
    const int g = r16 & 3;
    const int row = g * 48 + j;
    bsum[q] = dir ? (bi_bw[row] + bh_bw[row]) : (bi_fw[row] + bh_fw[row]);
  } else if (t < 39296) {
    const int q = t - 37248;
    const int i = q & 7, lane = (q >> 3) & 63, fid = q >> 9;
    const int k = ((lane >> 4) << 3) + i;
    const int r16 = lane & 15;
    float v = 0.0f;
    if (fid == 0) {
      if (r16 < 12 && k >= 12 && k < 24) v = msg_w[r16 * 12 + (k - 12)];
    } else {
      const int R = (fid - 1) * 16 + r16;
      const int kind = R / 12, j = R % 12;
      if (kind == 0)      v = (k < 12) ? gw_ih[j * 12 + k]          : ((k < 24) ? gw_hh[j * 12 + (k - 12)] : 0.0f);
      else if (kind == 1) v = (k < 12) ? gw_ih[(12 + j) * 12 + k]   : ((k < 24) ? gw_hh[(12 + j) * 12 + (k - 12)] : 0.0f);
      else if (kind == 2) v = (k < 12) ? gw_ih[(24 + j) * 12 + k]   : 0.0f;
      else                v = (k >= 12 && k < 24) ? gw_hh[(24 + j) * 12 + (k - 12)] : 0.0f;
    }
    mfrag[q] = __builtin_bit_cast(unsigned short, (_Float16)v);
  } else if (t < 39360) {
    const int q = t - 39296;
    if (q < 16) mbias[q] = (q < 12) ? msg_b[q] : 0.0f;
    else {
      const int R = q - 16, kind = R / 12, j = R % 12;
      float v;
      if (kind == 0)      v = gb_ih[j] + gb_hh[j];
      else if (kind == 1) v = gb_ih[12 + j] + gb_hh[12 + j];
      else if (kind == 2) v = gb_ih[24 + j];
      else                v = gb_hh[24 + j];
      mbias[q] = v;
    }
  }
}

// ---------------------------------------------------------------------------
// Phase A via MFMA (structure = round 7; all per-own-column u16 LDS traffic
// converted to paired u32 accesses: attention-mix reads were 8-way bank
// conflicts (100*(lane/4) mod 32 -> 8 banks), now 2-way unique + quad
// broadcast = free, and half the instructions).
// ---------------------------------------------------------------------------
__global__ __launch_bounds__(256) void msg_mfma_kernel(
    const float* __restrict__ nf, const float* __restrict__ pos,
    const float* __restrict__ att,
    const unsigned short* __restrict__ mfrag, const float* __restrict__ mbias,
    unsigned short* __restrict__ xth)
{
  __shared__ unsigned short B_lds[256][40];   // f16 bits, 80B rows
  __shared__ unsigned short g_lds[256][50];   // f16 bits, 100B rows

  const int tid  = threadIdx.x;
  const int lane = tid & 63;
  const int w    = __builtin_amdgcn_readfirstlane(tid >> 6);
  const int c16  = lane & 15;
  const int grp  = lane >> 4;
  const int own  = tid;
  const int node = own & 3;
  const int sl   = (own >> 6) * 16 + ((own >> 4) & 3) * 4 + ((own >> 2) & 3);

  half8 A1 = *reinterpret_cast<const half8*>(mfrag + (size_t)lane * 8);
  half8 A2[3];
#pragma unroll
  for (int mt = 0; mt < 3; ++mt)
    A2[mt] = *reinterpret_cast<const half8*>(mfrag + (size_t)((1 + mt) * 64 + lane) * 8);
  const f32x4 bias1 = *reinterpret_cast<const f32x4*>(mbias + grp * 4);
  f32x4 bias2[3];
#pragma unroll
  for (int mt = 0; mt < 3; ++mt)
    bias2[mt] = *reinterpret_cast<const f32x4*>(mbias + 16 + mt * 16 + grp * 4);

  {
    unsigned int* bz = reinterpret_cast<unsigned int*>(&B_lds[0][0]);
#pragma unroll
    for (int q = 0; q < 20; ++q) bz[tid * 20 + q] = 0u;
  }

  const int sid = blockIdx.x * 64 + sl;
  const int s   = sid >> 16;
  const int b   = sid & (NB - 1);
  float h[12];
  {
    const size_t ib = ((size_t)(b * SL + s) * 4 + node) * 6;
    const float2* n2 = (const float2*)(nf  + ib);
    const float2* p2 = (const float2*)(pos + ib);
#pragma unroll
    for (int q = 0; q < 3; q++) {
      float2 v = n2[q]; h[q*2]   = v.x; h[q*2+1]   = v.y;
      float2 u = p2[q]; h[6+q*2] = u.x; h[6+q*2+1] = u.y;
    }
  }
  float ta[4];
  {
    float4 v = *(const float4*)(att + ((size_t)(b * SL + s) * 4 + node) * 4);
    ta[0] = v.x; ta[1] = v.y; ta[2] = v.z; ta[3] = v.w;
  }
  {
    unsigned int* bp = (unsigned int*)&B_lds[own][0];
#pragma unroll
    for (int d = 0; d < 6; ++d) bp[6 + d] = pkh2(h[2*d], h[2*d+1]);
  }
  __syncthreads();

#pragma unroll 1
  for (int pass = 0; pass < 2; ++pass) {
    // --- GEMM1: m_all (rows 0..11) ---
#pragma unroll
    for (int nt = 0; nt < 4; ++nt) {
      const int col = w * 64 + nt * 16 + c16;
      half8 B = *reinterpret_cast<const half8*>(&B_lds[col][grp * 8]);
      f32x4 C = __builtin_amdgcn_mfma_f32_16x16x32_f16(A1, B, bias1, 0, 0, 0);
      if (grp < 3) {
        unsigned int* gp = (unsigned int*)&g_lds[col][0];
        gp[grp * 2]     = pkh2(C[0], C[1]);
        gp[grp * 2 + 1] = pkh2(C[2], C[3]);
      }
    }
    __syncthreads();

    // --- attention mix (paired u32 reads; quad-broadcast, conflict-free) ---
    {
      const int cb = own & ~3;
      float mv[12];
#pragma unroll
      for (int d = 0; d < 12; ++d) mv[d] = 0.0f;
#pragma unroll
      for (int ww = 0; ww < 4; ++ww) {
        const float a = ta[ww];
        const unsigned int* gp = (const unsigned int*)&g_lds[cb + ww][0];
#pragma unroll
        for (int dq = 0; dq < 6; ++dq) {
          const unsigned int u = gp[dq];
          mv[2*dq]   = __builtin_fmaf(a, loh(u), mv[2*dq]);
          mv[2*dq+1] = __builtin_fmaf(a, hih(u), mv[2*dq+1]);
        }
      }
      unsigned int* bp = (unsigned int*)&B_lds[own][0];
#pragma unroll
      for (int d = 0; d < 6; ++d) bp[d] = pkh2(mv[2*d], mv[2*d+1]);
    }
    __syncthreads();

    // --- GEMM2: gates, 48 rows = [r | z | n_ih | n_hh] ---
#pragma unroll
    for (int nt = 0; nt < 4; ++nt) {
      const int col = w * 64 + nt * 16 + c16;
      half8 B = *reinterpret_cast<const half8*>(&B_lds[col][grp * 8]);
      f32x4 C0 = __builtin_amdgcn_mfma_f32_16x16x32_f16(A2[0], B, bias2[0], 0, 0, 0);
      f32x4 C1 = __builtin_amdgcn_mfma_f32_16x16x32_f16(A2[1], B, bias2[1], 0, 0, 0);
      f32x4 C2 = __builtin_amdgcn_mfma_f32_16x16x32_f16(A2[2], B, bias2[2], 0, 0, 0);
      unsigned int* gp = (unsigned int*)&g_lds[col][0];
      gp[grp * 2]      = pkh2(C0[0], C0[1]);
      gp[grp * 2 + 1]  = pkh2(C0[2], C0[3]);
      gp[8 + grp * 2]     = pkh2(C1[0], C1[1]);
      gp[8 + grp * 2 + 1] = pkh2(C1[2], C1[3]);
      gp[16 + grp * 2]     = pkh2(C2[0], C2[1]);
      gp[16 + grp * 2 + 1] = pkh2(C2[2], C2[3]);
    }
    __syncthreads();

    // --- GRU update (paired u32 reads; stride 25 dw odd -> conflict-free) ---
    {
      const unsigned int* gq = (const unsigned int*)&g_lds[own][0];
#pragma unroll
      for (int jq = 0; jq < 6; ++jq) {
        const unsigned int ur = gq[jq];
        const unsigned int uz = gq[6 + jq];
        const unsigned int ui = gq[12 + jq];
        const unsigned int uh = gq[18 + jq];
        {
          const float r = sigm(loh(ur)), z = sigm(loh(uz));
          const float g = tanh_f(loh(ui) + r * loh(uh));
          h[2*jq] = (1.0f - z) * g + z * h[2*jq];
        }
        {
          const float r = sigm(hih(ur)), z = sigm(hih(uz));
          const float g = tanh_f(hih(ui) + r * hih(uh));
          h[2*jq+1] = (1.0f - z) * g + z * h[2*jq+1];
        }
      }
      unsigned int* bp = (unsigned int*)&B_lds[own][0];
#pragma unroll
      for (int d = 0; d < 6; ++d) bp[6 + d] = pkh2(h[2*d], h[2*d+1]);
    }
    __syncthreads();
  }

  // --- store: xth[(s*48+f)*NB + b], coalesced via LDS transpose ---
  const int b0 = (blockIdx.x * 64) & (NB - 1);
#pragma unroll
  for (int ff = 0; ff < 12; ++ff) {
    const int f  = w * 12 + ff;
    const int d  = f >> 2, nd = f & 3;
    const int i  = lane;
    const int cg = (i >> 4) * 64 + ((i >> 2) & 3) * 16 + (i & 3) * 4 + nd;
    xth[(size_t)(s * 48 + f) * NB + b0 + i] = B_lds[cg][12 + d];
  }
}

// ---------------------------------------------------------------------------
// Phase B+C: biLSTM via MFMA + MLP head.
// NEW (vs r7): last step writes h as f32 into batch-major hf[64][100]
// (aliases dead act buffer; odd-dword stride -> conflict-free), and the MLP
// reads activations as float4 (33 b128/wave vs 850 8-way-conflicted u16).
// LDS 48.6KB -> 39KB.
// ---------------------------------------------------------------------------
__global__ __launch_bounds__(512) void lstm_mfma_kernel(
    const unsigned short* __restrict__ xth,
    const unsigned short* __restrict__ wfrag,
    const float* __restrict__ bsum,
    const float* __restrict__ e1w, const float* __restrict__ e1b,
    const float* __restrict__ e2w, const float* __restrict__ e2b,
    const float* __restrict__ e3w, const float* __restrict__ e3b,
    float* __restrict__ out)
{
  __shared__ float4 pool4[2496];               // 39936 B
  float* pool = (float*)pool4;
  unsigned short* act = (unsigned short*)pool; // [2][64][104] halfs (26624 B)
  float* hf  = pool;                           // [64][100] f32 (aliases act; after loop)
  float* e1o = pool + 6656;                    // [64][52] f32
  float* e2o = pool;                           // [64][44] f32 (aliases hf; after e1)

  const int tid  = threadIdx.x;
  const int lane = tid & 63;
  const int w    = __builtin_amdgcn_readfirstlane(tid >> 6);
  const int dir  = w & 1;
  const int ug   = w >> 1;
  const int b0   = blockIdx.x * 64;
  const int col  = lane & 15;
  const int grp  = lane >> 4;

  half8 A[3][3];
#pragma unroll
  for (int mt = 0; mt < 3; ++mt)
#pragma unroll
    for (int kc = 0; kc < 3; ++kc) {
      const int fid = ((dir * 4 + ug) * 3 + mt) * 3 + kc;
      A[mt][kc] = *reinterpret_cast<const half8*>(wfrag + (size_t)(fid * 64 + lane) * 8);
    }
  f32x4 bias[3];
#pragma unroll
  for (int mt = 0; mt < 3; ++mt)
    bias[mt] = *reinterpret_cast<const f32x4*>(bsum + ((dir * 4 + ug) * 3 + mt) * 16 + grp * 4);

#pragma unroll
  for (int ff = 0; ff < 6; ++ff) {
    const int f = w * 6 + ff;
    act[(0 * 64 + lane) * 104 + f] = xth[(size_t)(0 * 48 + f) * NB + b0 + lane];
    act[(1 * 64 + lane) * 104 + f] = xth[(size_t)(4 * 48 + f) * NB + b0 + lane];
  }
#pragma unroll
  for (int jj = 0; jj < 12; ++jj)
    act[(dir * 64 + lane) * 104 + 48 + ug * 12 + jj] = 0;
  __syncthreads();

  float c[3][4];
#pragma unroll
  for (int mt = 0; mt < 3; ++mt)
#pragma unroll
    for (int nt = 0; nt < 4; ++nt) c[mt][nt] = 0.0f;

#pragma unroll 1
  for (int st = 0; st < 5; ++st) {
    float hvf[3][4];
#pragma unroll
    for (int nt = 0; nt < 4; ++nt) {
      const int n = nt * 16 + col;
      const unsigned short* ar = &act[(dir * 64 + n) * 104];
      half8 B0 = *reinterpret_cast<const half8*>(ar + grp * 8);
      half8 B1 = *reinterpret_cast<const half8*>(ar + 32 + grp * 8);
      half8 B2 = *reinterpret_cast<const half8*>(ar + 64 + grp * 8);
      f32x4 C0 = bias[0], C1 = bias[1], C2 = bias[2];
      C0 = __builtin_amdgcn_mfma_f32_16x16x32_f16(A[0][0], B0, C0, 0, 0, 0);
      C0 = __builtin_amdgcn_mfma_f32_16x16x32_f16(A[0][1], B1, C0, 0, 0, 0);
      C0 = __builtin_amdgcn_mfma_f32_16x16x32_f16(A[0][2], B2, C0, 0, 0, 0);
      C1 = __builtin_amdgcn_mfma_f32_16x16x32_f16(A[1][0], B0, C1, 0, 0, 0);
      C1 = __builtin_amdgcn_mfma_f32_16x16x32_f16(A[1][1], B1, C1, 0, 0, 0);
      C1 = __builtin_amdgcn_mfma_f32_16x16x32_f16(A[1][2], B2, C1, 0, 0, 0);
      C2 = __builtin_amdgcn_mfma_f32_16x16x32_f16(A[2][0], B0, C2, 0, 0, 0);
      C2 = __builtin_amdgcn_mfma_f32_16x16x32_f16(A[2][1], B1, C2, 0, 0, 0);
      C2 = __builtin_amdgcn_mfma_f32_16x16x32_f16(A[2][2], B2, C2, 0, 0, 0);
#pragma unroll
      for (int mt = 0; mt < 3; ++mt) {
        const f32x4 C = (mt == 0) ? C0 : (mt == 1) ? C1 : C2;
        const float cc = sigm(C[1]) * c[mt][nt] + sigm(C[0]) * tanh_f(C[2]);
        c[mt][nt] = cc;
        hvf[mt][nt] = sigm(C[3]) * tanh_f(cc);
      }
    }
    __syncthreads();                       // all act reads complete
    if (st < 4) {
#pragma unroll
      for (int mt = 0; mt < 3; ++mt)
#pragma unroll
        for (int nt = 0; nt < 4; ++nt)
          act[(dir * 64 + nt * 16 + col) * 104 + 48 + ug * 12 + mt * 4 + grp] =
              __builtin_bit_cast(unsigned short, (_Float16)hvf[mt][nt]);
      const int s0 = st + 1, s1 = 3 - st;
#pragma unroll
      for (int ff = 0; ff < 6; ++ff) {
        const int f = w * 6 + ff;
        act[(0 * 64 + lane) * 104 + f] = xth[(size_t)(s0 * 48 + f) * NB + b0 + lane];
        act[(1 * 64 + lane) * 104 + f] = xth[(size_t)(s1 * 48 + f) * NB + b0 + lane];
      }
    } else {
      // final h -> f32 batch-major hf[64][100] (aliases act; reads are done)
#pragma unroll
      for (int mt = 0; mt < 3; ++mt)
#pragma unroll
        for (int nt = 0; nt < 4; ++nt)
          hf[(nt * 16 + col) * 100 + dir * 48 + ug * 12 + mt * 4 + grp] = hvf[mt][nt];
    }
    __syncthreads();
  }

  // ---- MLP head: float4 activation reads, accumulators hoisted ----
  // e1: 48 rows = 8 waves x 6; reads hf (12 b128/wave, conflict-free)
  {
    float acc[6];
#pragma unroll
    for (int r = 0; r < 6; ++r) acc[r] = e1b[w * 6 + r];
#pragma unroll
    for (int q = 0; q < 24; ++q) {
      const float4 v = *reinterpret_cast<const float4*>(&hf[lane * 100 + q * 4]);
#pragma unroll
      for (int r = 0; r < 6; ++r) {
        const int rr = w * 6 + r;
        acc[r] = __builtin_fmaf(e1w[rr * 96 + q * 4 + 0], v.x, acc[r]);
        acc[r] = __builtin_fmaf(e1w[rr * 96 + q * 4 + 1], v.y, acc[r]);
        acc[r] = __builtin_fmaf(e1w[rr * 96 + q * 4 + 2], v.z, acc[r]);
        acc[r] = __builtin_fmaf(e1w[rr * 96 + q * 4 + 3], v.w, acc[r]);
      }
    }
    __syncthreads();                      // hf reads done before e1o write? (separate region, but cheap)
#pragma unroll
    for (int r = 0; r < 6; ++r)
      e1o[lane * 52 + w * 6 + r] = acc[r] > 0.0f ? acc[r] : 0.0f;
  }
  __syncthreads();

  // e2: 36 rows split 5,5,5,5,4,4,4,4; reads e1o (12 b128/wave); writes e2o (aliases hf)
  {
    const int e2base = (w < 4) ? w * 5 : 20 + (w - 4) * 4;
    const int e2cnt  = (w < 4) ? 5 : 4;
    float acc[5];
#pragma unroll
    for (int r = 0; r < 5; ++r) acc[r] = (r < e2cnt) ? e2b[e2base + r] : 0.0f;
#pragma unroll
    for (int q = 0; q < 12; ++q) {
      const float4 v = *reinterpret_cast<const float4*>(&e1o[lane * 52 + q * 4]);
#pragma unroll
      for (int r = 0; r < 5; ++r) {
        if (r < e2cnt) {
          const int rr = e2base + r;
          acc[r] = __builtin_fmaf(e2w[rr * 48 + q * 4 + 0], v.x, acc[r]);
          acc[r] = __builtin_fmaf(e2w[rr * 48 + q * 4 + 1], v.y, acc[r]);
          acc[r] = __builtin_fmaf(e2w[rr * 48 + q * 4 + 2], v.z, acc[r]);
          acc[r] = __builtin_fmaf(e2w[rr * 48 + q * 4 + 3], v.w, acc[r]);
        }
      }
    }
    __syncthreads();                      // all e1/hf reads done before overwriting hf region
#pragma unroll
    for (int r = 0; r < 5; ++r)
      if (r < e2cnt) e2o[lane * 44 + e2base + r] = acc[r] > 0.0f ? acc[r] : 0.0f;
  }
  __syncthreads();

  // e3: 6 rows, one per wave; reads e2o (9 b128/wave)
  if (w < 6) {
    float a = e3b[w];
#pragma unroll
    for (int q = 0; q < 9; ++q) {
      const float4 v = *reinterpret_cast<const float4*>(&e2o[lane * 44 + q * 4]);
      a = __builtin_fmaf(e3w[w * 36 + q * 4 + 0], v.x, a);
      a = __builtin_fmaf(e3w[w * 36 + q * 4 + 1], v.y, a);
      a = __builtin_fmaf(e3w[w * 36 + q * 4 + 2], v.z, a);
      a = __builtin_fmaf(e3w[w * 36 + q * 4 + 3], v.w, a);
    }
    out[(size_t)(b0 + lane) * 6 + w] = a;
  }
}

extern "C" void kernel_launch(void* const* d_in, const int* in_sizes, int n_in,
                              void* d_out, int out_size, void* d_ws, size_t ws_size,
                              hipStream_t stream)
{
  const float* nf    = (const float*)d_in[0];
  const float* pos   = (const float*)d_in[1];
  const float* att   = (const float*)d_in[2];
  const float* msg_w = (const float*)d_in[3];
  const float* msg_b = (const float*)d_in[4];
  const float* gw_ih = (const float*)d_in[5];
  const float* gw_hh = (const float*)d_in[6];
  const float* gb_ih = (const float*)d_in[7];
  const float* gb_hh = (const float*)d_in[8];
  const float* wi_fw = (const float*)d_in[9];
  const float* wh_fw = (const float*)d_in[10];
  const float* bi_fw = (const float*)d_in[11];
  const float* bh_fw = (const float*)d_in[12];
  const float* wi_bw = (const float*)d_in[13];
  const float* wh_bw = (const float*)d_in[14];
  const float* bi_bw = (const float*)d_in[15];
  const float* bh_bw = (const float*)d_in[16];
  const float* e1w   = (const float*)d_in[17];
  const float* e1b   = (const float*)d_in[18];
  const float* e2w   = (const float*)d_in[19];
  const float* e2b   = (const float*)d_in[20];
  const float* e3w   = (const float*)d_in[21];
  const float* e3b   = (const float*)d_in[22];

  unsigned short* xth   = (unsigned short*)d_ws;
  unsigned short* wfrag = xth + (size_t)SL * 48 * NB;
  float*          bsum  = (float*)(wfrag + 36864);
  unsigned short* mfrag = (unsigned short*)(bsum + 384);
  float*          mbias = (float*)(mfrag + 2048);
  float*          outp  = (float*)d_out;

  prep_kernel<<<154, 256, 0, stream>>>(
      wi_fw, wh_fw, bi_fw, bh_fw, wi_bw, wh_bw, bi_bw, bh_bw,
      msg_w, msg_b, gw_ih, gw_hh, gb_ih, gb_hh,
      wfrag, bsum, mfrag, mbias);

  msg_mfma_kernel<<<(NB * SL) / 64, 256, 0, stream>>>(
      nf, pos, att, mfrag, mbias, xth);

  lstm_mfma_kernel<<<NB / 64, 512, 0, stream>>>(
      xth, wfrag, bsum, e1w, e1b, e2w, e2b, e3w, e3b, outp);
}

// Round 9
// 133.407 us; speedup vs baseline: 12.0362x; 1.3923x over previous
//
#include <hip/hip_runtime.h>
#include <cstddef>

#define NB 65536
#define SL 5

typedef _Float16 f16;
typedef f16 half8 __attribute__((ext_vector_type(8)));
typedef float f32x4 __attribute__((ext_vector_type(4)));

// Fast 1-ulp reciprocal (v_rcp_f32) instead of IEEE divide microcode
// (v_div_scale + NR + div_fixup ~ 8-9 inst each; 300 divides/thread in the
// LSTM epilogue were the hidden 4x VALU inflation found in round 8).
__device__ __forceinline__ float sigm(float x) {
  return __builtin_amdgcn_rcpf(1.0f + __expf(-x));
}
__device__ __forceinline__ float tanh_f(float x) {
  return __builtin_fmaf(2.0f, __builtin_amdgcn_rcpf(1.0f + __expf(-2.0f * x)), -1.0f);
}
__device__ __forceinline__ unsigned int pkh2(float a, float b) {
  return (unsigned int)__builtin_bit_cast(unsigned short, (_Float16)a)
       | ((unsigned int)__builtin_bit_cast(unsigned short, (_Float16)b) << 16);
}
__device__ __forceinline__ float loh(unsigned int u) {
  return (float)__builtin_bit_cast(_Float16, (unsigned short)(u & 0xffffu));
}
__device__ __forceinline__ float hih(unsigned int u) {
  return (float)__builtin_bit_cast(_Float16, (unsigned short)(u >> 16));
}

// ---------------------------------------------------------------------------
// prep: f16 MFMA A-fragments (unchanged).
// ---------------------------------------------------------------------------
__global__ __launch_bounds__(256) void prep_kernel(
    const float* __restrict__ wi_fw, const float* __restrict__ wh_fw,
    const float* __restrict__ bi_fw, const float* __restrict__ bh_fw,
    const float* __restrict__ wi_bw, const float* __restrict__ wh_bw,
    const float* __restrict__ bi_bw, const float* __restrict__ bh_bw,
    const float* __restrict__ msg_w, const float* __restrict__ msg_b,
    const float* __restrict__ gw_ih, const float* __restrict__ gw_hh,
    const float* __restrict__ gb_ih, const float* __restrict__ gb_hh,
    unsigned short* __restrict__ wfrag, float* __restrict__ bsum,
    unsigned short* __restrict__ mfrag, float* __restrict__ mbias)
{
  const int t = blockIdx.x * 256 + threadIdx.x;
  if (t < 36864) {
    const int i = t & 7, lane = (t >> 3) & 63, fid = t >> 9;
    const int kc = fid % 3, mt = (fid / 3) % 3, ug = (fid / 9) & 3, dir = fid / 36;
    const int k = kc * 32 + (lane >> 4) * 8 + i;
    const int r16 = lane & 15;
    const int j = ug * 12 + mt * 4 + (r16 >> 2);
    const int g = r16 & 3;
    const float* wi = dir ? wi_bw : wi_fw;
    const float* wh = dir ? wh_bw : wh_fw;
    const float v = (k < 48) ? wi[(g * 48 + j) * 48 + k] : wh[(g * 48 + j) * 48 + (k - 48)];
    wfrag[t] = __builtin_bit_cast(unsigned short, (_Float16)v);
  } else if (t < 37248) {
    const int q = t - 36864;
    const int r16 = q & 15, mt = (q >> 4) % 3, ug = (q / 48) & 3, dir = q / 192;
    const int j = ug * 12 + mt * 4 + (r16 >> 2);
    const int g = r16 & 3;
    const int row = g * 48 + j;
    bsum[q] = dir ? (bi_bw[row] + bh_bw[row]) : (bi_fw[row] + bh_fw[row]);
  } else if (t < 39296) {
    const int q = t - 37248;
    const int i = q & 7, lane = (q >> 3) & 63, fid = q >> 9;
    const int k = ((lane >> 4) << 3) + i;
    const int r16 = lane & 15;
    float v = 0.0f;
    if (fid == 0) {
      if (r16 < 12 && k >= 12 && k < 24) v = msg_w[r16 * 12 + (k - 12)];
    } else {
      const int R = (fid - 1) * 16 + r16;
      const int kind = R / 12, j = R % 12;
      if (kind == 0)      v = (k < 12) ? gw_ih[j * 12 + k]          : ((k < 24) ? gw_hh[j * 12 + (k - 12)] : 0.0f);
      else if (kind == 1) v = (k < 12) ? gw_ih[(12 + j) * 12 + k]   : ((k < 24) ? gw_hh[(12 + j) * 12 + (k - 12)] : 0.0f);
      else if (kind == 2) v = (k < 12) ? gw_ih[(24 + j) * 12 + k]   : 0.0f;
      else                v = (k >= 12 && k < 24) ? gw_hh[(24 + j) * 12 + (k - 12)] : 0.0f;
    }
    mfrag[q] = __builtin_bit_cast(unsigned short, (_Float16)v);
  } else if (t < 39360) {
    const int q = t - 39296;
    if (q < 16) mbias[q] = (q < 12) ? msg_b[q] : 0.0f;
    else {
      const int R = q - 16, kind = R / 12, j = R % 12;
      float v;
      if (kind == 0)      v = gb_ih[j] + gb_hh[j];
      else if (kind == 1) v = gb_ih[12 + j] + gb_hh[12 + j];
      else if (kind == 2) v = gb_ih[24 + j];
      else                v = gb_hh[24 + j];
      mbias[q] = v;
    }
  }
}

// ---------------------------------------------------------------------------
// Phase A via MFMA (unchanged structure; helpers now use fast rcp).
// ---------------------------------------------------------------------------
__global__ __launch_bounds__(256) void msg_mfma_kernel(
    const float* __restrict__ nf, const float* __restrict__ pos,
    const float* __restrict__ att,
    const unsigned short* __restrict__ mfrag, const float* __restrict__ mbias,
    unsigned short* __restrict__ xth)
{
  __shared__ unsigned short B_lds[256][40];   // f16 bits, 80B rows
  __shared__ unsigned short g_lds[256][50];   // f16 bits, 100B rows

  const int tid  = threadIdx.x;
  const int lane = tid & 63;
  const int w    = __builtin_amdgcn_readfirstlane(tid >> 6);
  const int c16  = lane & 15;
  const int grp  = lane >> 4;
  const int own  = tid;
  const int node = own & 3;
  const int sl   = (own >> 6) * 16 + ((own >> 4) & 3) * 4 + ((own >> 2) & 3);

  half8 A1 = *reinterpret_cast<const half8*>(mfrag + (size_t)lane * 8);
  half8 A2[3];
#pragma unroll
  for (int mt = 0; mt < 3; ++mt)
    A2[mt] = *reinterpret_cast<const half8*>(mfrag + (size_t)((1 + mt) * 64 + lane) * 8);
  const f32x4 bias1 = *reinterpret_cast<const f32x4*>(mbias + grp * 4);
  f32x4 bias2[3];
#pragma unroll
  for (int mt = 0; mt < 3; ++mt)
    bias2[mt] = *reinterpret_cast<const f32x4*>(mbias + 16 + mt * 16 + grp * 4);

  {
    unsigned int* bz = reinterpret_cast<unsigned int*>(&B_lds[0][0]);
#pragma unroll
    for (int q = 0; q < 20; ++q) bz[tid * 20 + q] = 0u;
  }

  const int sid = blockIdx.x * 64 + sl;
  const int s   = sid >> 16;
  const int b   = sid & (NB - 1);
  float h[12];
  {
    const size_t ib = ((size_t)(b * SL + s) * 4 + node) * 6;
    const float2* n2 = (const float2*)(nf  + ib);
    const float2* p2 = (const float2*)(pos + ib);
#pragma unroll
    for (int q = 0; q < 3; q++) {
      float2 v = n2[q]; h[q*2]   = v.x; h[q*2+1]   = v.y;
      float2 u = p2[q]; h[6+q*2] = u.x; h[6+q*2+1] = u.y;
    }
  }
  float ta[4];
  {
    float4 v = *(const float4*)(att + ((size_t)(b * SL + s) * 4 + node) * 4);
    ta[0] = v.x; ta[1] = v.y; ta[2] = v.z; ta[3] = v.w;
  }
  {
    unsigned int* bp = (unsigned int*)&B_lds[own][0];
#pragma unroll
    for (int d = 0; d < 6; ++d) bp[6 + d] = pkh2(h[2*d], h[2*d+1]);
  }
  __syncthreads();

#pragma unroll 1
  for (int pass = 0; pass < 2; ++pass) {
    // --- GEMM1: m_all (rows 0..11) ---
#pragma unroll
    for (int nt = 0; nt < 4; ++nt) {
      const int col = w * 64 + nt * 16 + c16;
      half8 B = *reinterpret_cast<const half8*>(&B_lds[col][grp * 8]);
      f32x4 C = __builtin_amdgcn_mfma_f32_16x16x32_f16(A1, B, bias1, 0, 0, 0);
      if (grp < 3) {
        unsigned int* gp = (unsigned int*)&g_lds[col][0];
        gp[grp * 2]     = pkh2(C[0], C[1]);
        gp[grp * 2 + 1] = pkh2(C[2], C[3]);
      }
    }
    __syncthreads();

    // --- attention mix (paired u32 reads; quad-broadcast) ---
    {
      const int cb = own & ~3;
      float mv[12];
#pragma unroll
      for (int d = 0; d < 12; ++d) mv[d] = 0.0f;
#pragma unroll
      for (int ww = 0; ww < 4; ++ww) {
        const float a = ta[ww];
        const unsigned int* gp = (const unsigned int*)&g_lds[cb + ww][0];
#pragma unroll
        for (int dq = 0; dq < 6; ++dq) {
          const unsigned int u = gp[dq];
          mv[2*dq]   = __builtin_fmaf(a, loh(u), mv[2*dq]);
          mv[2*dq+1] = __builtin_fmaf(a, hih(u), mv[2*dq+1]);
        }
      }
      unsigned int* bp = (unsigned int*)&B_lds[own][0];
#pragma unroll
      for (int d = 0; d < 6; ++d) bp[d] = pkh2(mv[2*d], mv[2*d+1]);
    }
    __syncthreads();

    // --- GEMM2: gates, 48 rows = [r | z | n_ih | n_hh] ---
#pragma unroll
    for (int nt = 0; nt < 4; ++nt) {
      const int col = w * 64 + nt * 16 + c16;
      half8 B = *reinterpret_cast<const half8*>(&B_lds[col][grp * 8]);
      f32x4 C0 = __builtin_amdgcn_mfma_f32_16x16x32_f16(A2[0], B, bias2[0], 0, 0, 0);
      f32x4 C1 = __builtin_amdgcn_mfma_f32_16x16x32_f16(A2[1], B, bias2[1], 0, 0, 0);
      f32x4 C2 = __builtin_amdgcn_mfma_f32_16x16x32_f16(A2[2], B, bias2[2], 0, 0, 0);
      unsigned int* gp = (unsigned int*)&g_lds[col][0];
      gp[grp * 2]      = pkh2(C0[0], C0[1]);
      gp[grp * 2 + 1]  = pkh2(C0[2], C0[3]);
      gp[8 + grp * 2]     = pkh2(C1[0], C1[1]);
      gp[8 + grp * 2 + 1] = pkh2(C1[2], C1[3]);
      gp[16 + grp * 2]     = pkh2(C2[0], C2[1]);
      gp[16 + grp * 2 + 1] = pkh2(C2[2], C2[3]);
    }
    __syncthreads();

    // --- GRU update (paired u32 reads) ---
    {
      const unsigned int* gq = (const unsigned int*)&g_lds[own][0];
#pragma unroll
      for (int jq = 0; jq < 6; ++jq) {
        const unsigned int ur = gq[jq];
        const unsigned int uz = gq[6 + jq];
        const unsigned int ui = gq[12 + jq];
        const unsigned int uh = gq[18 + jq];
        {
          const float r = sigm(loh(ur)), z = sigm(loh(uz));
          const float g = tanh_f(loh(ui) + r * loh(uh));
          h[2*jq] = (1.0f - z) * g + z * h[2*jq];
        }
        {
          const float r = sigm(hih(ur)), z = sigm(hih(uz));
          const float g = tanh_f(hih(ui) + r * hih(uh));
          h[2*jq+1] = (1.0f - z) * g + z * h[2*jq+1];
        }
      }
      unsigned int* bp = (unsigned int*)&B_lds[own][0];
#pragma unroll
      for (int d = 0; d < 6; ++d) bp[6 + d] = pkh2(h[2*d], h[2*d+1]);
    }
    __syncthreads();
  }

  // --- store: xth[(s*48+f)*NB + b], coalesced via LDS transpose ---
  const int b0 = (blockIdx.x * 64) & (NB - 1);
#pragma unroll
  for (int ff = 0; ff < 12; ++ff) {
    const int f  = w * 12 + ff;
    const int d  = f >> 2, nd = f & 3;
    const int i  = lane;
    const int cg = (i >> 4) * 64 + ((i >> 2) & 3) * 16 + (i & 3) * 4 + nd;
    xth[(size_t)(s * 48 + f) * NB + b0 + i] = B_lds[cg][12 + d];
  }
}

// ---------------------------------------------------------------------------
// Phase B+C: biLSTM via MFMA + MLP head (unchanged structure; fast rcp).
// ---------------------------------------------------------------------------
__global__ __launch_bounds__(512) void lstm_mfma_kernel(
    const unsigned short* __restrict__ xth,
    const unsigned short* __restrict__ wfrag,
    const float* __restrict__ bsum,
    const float* __restrict__ e1w, const float* __restrict__ e1b,
    const float* __restrict__ e2w, const float* __restrict__ e2b,
    const float* __restrict__ e3w, const float* __restrict__ e3b,
    float* __restrict__ out)
{
  __shared__ float4 pool4[2496];               // 39936 B
  float* pool = (float*)pool4;
  unsigned short* act = (unsigned short*)pool; // [2][64][104] halfs (26624 B)
  float* hf  = pool;                           // [64][100] f32 (aliases act; after loop)
  float* e1o = pool + 6656;                    // [64][52] f32
  float* e2o = pool;                           // [64][44] f32 (aliases hf; after e1)

  const int tid  = threadIdx.x;
  const int lane = tid & 63;
  const int w    = __builtin_amdgcn_readfirstlane(tid >> 6);
  const int dir  = w & 1;
  const int ug   = w >> 1;
  const int b0   = blockIdx.x * 64;
  const int col  = lane & 15;
  const int grp  = lane >> 4;

  half8 A[3][3];
#pragma unroll
  for (int mt = 0; mt < 3; ++mt)
#pragma unroll
    for (int kc = 0; kc < 3; ++kc) {
      const int fid = ((dir * 4 + ug) * 3 + mt) * 3 + kc;
      A[mt][kc] = *reinterpret_cast<const half8*>(wfrag + (size_t)(fid * 64 + lane) * 8);
    }
  f32x4 bias[3];
#pragma unroll
  for (int mt = 0; mt < 3; ++mt)
    bias[mt] = *reinterpret_cast<const f32x4*>(bsum + ((dir * 4 + ug) * 3 + mt) * 16 + grp * 4);

#pragma unroll
  for (int ff = 0; ff < 6; ++ff) {
    const int f = w * 6 + ff;
    act[(0 * 64 + lane) * 104 + f] = xth[(size_t)(0 * 48 + f) * NB + b0 + lane];
    act[(1 * 64 + lane) * 104 + f] = xth[(size_t)(4 * 48 + f) * NB + b0 + lane];
  }
#pragma unroll
  for (int jj = 0; jj < 12; ++jj)
    act[(dir * 64 + lane) * 104 + 48 + ug * 12 + jj] = 0;
  __syncthreads();

  float c[3][4];
#pragma unroll
  for (int mt = 0; mt < 3; ++mt)
#pragma unroll
    for (int nt = 0; nt < 4; ++nt) c[mt][nt] = 0.0f;

#pragma unroll 1
  for (int st = 0; st < 5; ++st) {
    float hvf[3][4];
#pragma unroll
    for (int nt = 0; nt < 4; ++nt) {
      const int n = nt * 16 + col;
      const unsigned short* ar = &act[(dir * 64 + n) * 104];
      half8 B0 = *reinterpret_cast<const half8*>(ar + grp * 8);
      half8 B1 = *reinterpret_cast<const half8*>(ar + 32 + grp * 8);
      half8 B2 = *reinterpret_cast<const half8*>(ar + 64 + grp * 8);
      f32x4 C0 = bias[0], C1 = bias[1], C2 = bias[2];
      C0 = __builtin_amdgcn_mfma_f32_16x16x32_f16(A[0][0], B0, C0, 0, 0, 0);
      C0 = __builtin_amdgcn_mfma_f32_16x16x32_f16(A[0][1], B1, C0, 0, 0, 0);
      C0 = __builtin_amdgcn_mfma_f32_16x16x32_f16(A[0][2], B2, C0, 0, 0, 0);
      C1 = __builtin_amdgcn_mfma_f32_16x16x32_f16(A[1][0], B0, C1, 0, 0, 0);
      C1 = __builtin_amdgcn_mfma_f32_16x16x32_f16(A[1][1], B1, C1, 0, 0, 0);
      C1 = __builtin_amdgcn_mfma_f32_16x16x32_f16(A[1][2], B2, C1, 0, 0, 0);
      C2 = __builtin_amdgcn_mfma_f32_16x16x32_f16(A[2][0], B0, C2, 0, 0, 0);
      C2 = __builtin_amdgcn_mfma_f32_16x16x32_f16(A[2][1], B1, C2, 0, 0, 0);
      C2 = __builtin_amdgcn_mfma_f32_16x16x32_f16(A[2][2], B2, C2, 0, 0, 0);
#pragma unroll
      for (int mt = 0; mt < 3; ++mt) {
        const f32x4 C = (mt == 0) ? C0 : (mt == 1) ? C1 : C2;
        const float cc = sigm(C[1]) * c[mt][nt] + sigm(C[0]) * tanh_f(C[2]);
        c[mt][nt] = cc;
        hvf[mt][nt] = sigm(C[3]) * tanh_f(cc);
      }
    }
    __syncthreads();                       // all act reads complete
    if (st < 4) {
#pragma unroll
      for (int mt = 0; mt < 3; ++mt)
#pragma unroll
        for (int nt = 0; nt < 4; ++nt)
          act[(dir * 64 + nt * 16 + col) * 104 + 48 + ug * 12 + mt * 4 + grp] =
              __builtin_bit_cast(unsigned short, (_Float16)hvf[mt][nt]);
      const int s0 = st + 1, s1 = 3 - st;
#pragma unroll
      for (int ff = 0; ff < 6; ++ff) {
        const int f = w * 6 + ff;
        act[(0 * 64 + lane) * 104 + f] = xth[(size_t)(s0 * 48 + f) * NB + b0 + lane];
        act[(1 * 64 + lane) * 104 + f] = xth[(size_t)(s1 * 48 + f) * NB + b0 + lane];
      }
    } else {
      // final h -> f32 batch-major hf[64][100]
#pragma unroll
      for (int mt = 0; mt < 3; ++mt)
#pragma unroll
        for (int nt = 0; nt < 4; ++nt)
          hf[(nt * 16 + col) * 100 + dir * 48 + ug * 12 + mt * 4 + grp] = hvf[mt][nt];
    }
    __syncthreads();
  }

  // ---- MLP head: float4 activation reads, accumulators hoisted ----
  {
    float acc[6];
#pragma unroll
    for (int r = 0; r < 6; ++r) acc[r] = e1b[w * 6 + r];
#pragma unroll
    for (int q = 0; q < 24; ++q) {
      const float4 v = *reinterpret_cast<const float4*>(&hf[lane * 100 + q * 4]);
#pragma unroll
      for (int r = 0; r < 6; ++r) {
        const int rr = w * 6 + r;
        acc[r] = __builtin_fmaf(e1w[rr * 96 + q * 4 + 0], v.x, acc[r]);
        acc[r] = __builtin_fmaf(e1w[rr * 96 + q * 4 + 1], v.y, acc[r]);
        acc[r] = __builtin_fmaf(e1w[rr * 96 + q * 4 + 2], v.z, acc[r]);
        acc[r] = __builtin_fmaf(e1w[rr * 96 + q * 4 + 3], v.w, acc[r]);
      }
    }
    __syncthreads();
#pragma unroll
    for (int r = 0; r < 6; ++r)
      e1o[lane * 52 + w * 6 + r] = acc[r] > 0.0f ? acc[r] : 0.0f;
  }
  __syncthreads();

  {
    const int e2base = (w < 4) ? w * 5 : 20 + (w - 4) * 4;
    const int e2cnt  = (w < 4) ? 5 : 4;
    float acc[5];
#pragma unroll
    for (int r = 0; r < 5; ++r) acc[r] = (r < e2cnt) ? e2b[e2base + r] : 0.0f;
#pragma unroll
    for (int q = 0; q < 12; ++q) {
      const float4 v = *reinterpret_cast<const float4*>(&e1o[lane * 52 + q * 4]);
#pragma unroll
      for (int r = 0; r < 5; ++r) {
        if (r < e2cnt) {
          const int rr = e2base + r;
          acc[r] = __builtin_fmaf(e2w[rr * 48 + q * 4 + 0], v.x, acc[r]);
          acc[r] = __builtin_fmaf(e2w[rr * 48 + q * 4 + 1], v.y, acc[r]);
          acc[r] = __builtin_fmaf(e2w[rr * 48 + q * 4 + 2], v.z, acc[r]);
          acc[r] = __builtin_fmaf(e2w[rr * 48 + q * 4 + 3], v.w, acc[r]);
        }
      }
    }
    __syncthreads();
#pragma unroll
    for (int r = 0; r < 5; ++r)
      if (r < e2cnt) e2o[lane * 44 + e2base + r] = acc[r] > 0.0f ? acc[r] : 0.0f;
  }
  __syncthreads();

  if (w < 6) {
    float a = e3b[w];
#pragma unroll
    for (int q = 0; q < 9; ++q) {
      const float4 v = *reinterpret_cast<const float4*>(&e2o[lane * 44 + q * 4]);
      a = __builtin_fmaf(e3w[w * 36 + q * 4 + 0], v.x, a);
      a = __builtin_fmaf(e3w[w * 36 + q * 4 + 1], v.y, a);
      a = __builtin_fmaf(e3w[w * 36 + q * 4 + 2], v.z, a);
      a = __builtin_fmaf(e3w[w * 36 + q * 4 + 3], v.w, a);
    }
    out[(size_t)(b0 + lane) * 6 + w] = a;
  }
}

extern "C" void kernel_launch(void* const* d_in, const int* in_sizes, int n_in,
                              void* d_out, int out_size, void* d_ws, size_t ws_size,
                              hipStream_t stream)
{
  const float* nf    = (const float*)d_in[0];
  const float* pos   = (const float*)d_in[1];
  const float* att   = (const float*)d_in[2];
  const float* msg_w = (const float*)d_in[3];
  const float* msg_b = (const float*)d_in[4];
  const float* gw_ih = (const float*)d_in[5];
  const float* gw_hh = (const float*)d_in[6];
  const float* gb_ih = (const float*)d_in[7];
  const float* gb_hh = (const float*)d_in[8];
  const float* wi_fw = (const float*)d_in[9];
  const float* wh_fw = (const float*)d_in[10];
  const float* bi_fw = (const float*)d_in[11];
  const float* bh_fw = (const float*)d_in[12];
  const float* wi_bw = (const float*)d_in[13];
  const float* wh_bw = (const float*)d_in[14];
  const float* bi_bw = (const float*)d_in[15];
  const float* bh_bw = (const float*)d_in[16];
  const float* e1w   = (const float*)d_in[17];
  const float* e1b   = (const float*)d_in[18];
  const float* e2w   = (const float*)d_in[19];
  const float* e2b   = (const float*)d_in[20];
  const float* e3w   = (const float*)d_in[21];
  const float* e3b   = (const float*)d_in[22];

  unsigned short* xth   = (unsigned short*)d_ws;
  unsigned short* wfrag = xth + (size_t)SL * 48 * NB;
  float*          bsum  = (float*)(wfrag + 36864);
  unsigned short* mfrag = (unsigned short*)(bsum + 384);
  float*          mbias = (float*)(mfrag + 2048);
  float*          outp  = (float*)d_out;

  prep_kernel<<<154, 256, 0, stream>>>(
      wi_fw, wh_fw, bi_fw, bh_fw, wi_bw, wh_bw, bi_bw, bh_bw,
      msg_w, msg_b, gw_ih, gw_hh, gb_ih, gb_hh,
      wfrag, bsum, mfrag, mbias);

  msg_mfma_kernel<<<(NB * SL) / 64, 256, 0, stream>>>(
      nf, pos, att, mfrag, mbias, xth);

  lstm_mfma_kernel<<<NB / 64, 512, 0, stream>>>(
      xth, wfrag, bsum, e1w, e1b, e2w, e2b, e3w, e3b, outp);
}

// Round 10
// 127.379 us; speedup vs baseline: 12.6058x; 1.0473x over previous
//
#include <hip/hip_runtime.h>
#include <cstddef>

#define NB 65536
#define SL 5

typedef _Float16 f16;
typedef f16 half8 __attribute__((ext_vector_type(8)));
typedef float f32x4 __attribute__((ext_vector_type(4)));

// Fast 1-ulp reciprocal (v_rcp_f32) instead of IEEE divide microcode.
__device__ __forceinline__ float sigm(float x) {
  return __builtin_amdgcn_rcpf(1.0f + __expf(-x));
}
__device__ __forceinline__ float tanh_f(float x) {
  return __builtin_fmaf(2.0f, __builtin_amdgcn_rcpf(1.0f + __expf(-2.0f * x)), -1.0f);
}
__device__ __forceinline__ unsigned int pkh2(float a, float b) {
  return (unsigned int)__builtin_bit_cast(unsigned short, (_Float16)a)
       | ((unsigned int)__builtin_bit_cast(unsigned short, (_Float16)b) << 16);
}
__device__ __forceinline__ float loh(unsigned int u) {
  return (float)__builtin_bit_cast(_Float16, (unsigned short)(u & 0xffffu));
}
__device__ __forceinline__ float hih(unsigned int u) {
  return (float)__builtin_bit_cast(_Float16, (unsigned short)(u >> 16));
}

// ---------------------------------------------------------------------------
// prep: f16 MFMA A-fragments (unchanged).
// ---------------------------------------------------------------------------
__global__ __launch_bounds__(256) void prep_kernel(
    const float* __restrict__ wi_fw, const float* __restrict__ wh_fw,
    const float* __restrict__ bi_fw, const float* __restrict__ bh_fw,
    const float* __restrict__ wi_bw, const float* __restrict__ wh_bw,
    const float* __restrict__ bi_bw, const float* __restrict__ bh_bw,
    const float* __restrict__ msg_w, const float* __restrict__ msg_b,
    const float* __restrict__ gw_ih, const float* __restrict__ gw_hh,
    const float* __restrict__ gb_ih, const float* __restrict__ gb_hh,
    unsigned short* __restrict__ wfrag, float* __restrict__ bsum,
    unsigned short* __restrict__ mfrag, float* __restrict__ mbias)
{
  const int t = blockIdx.x * 256 + threadIdx.x;
  if (t < 36864) {
    const int i = t & 7, lane = (t >> 3) & 63, fid = t >> 9;
    const int kc = fid % 3, mt = (fid / 3) % 3, ug = (fid / 9) & 3, dir = fid / 36;
    const int k = kc * 32 + (lane >> 4) * 8 + i;
    const int r16 = lane & 15;
    const int j = ug * 12 + mt * 4 + (r16 >> 2);
    const int g = r16 & 3;
    const float* wi = dir ? wi_bw : wi_fw;
    const float* wh = dir ? wh_bw : wh_fw;
    const float v = (k < 48) ? wi[(g * 48 + j) * 48 + k] : wh[(g * 48 + j) * 48 + (k - 48)];
    wfrag[t] = __builtin_bit_cast(unsigned short, (_Float16)v);
  } else if (t < 37248) {
    const int q = t - 36864;
    const int r16 = q & 15, mt = (q >> 4) % 3, ug = (q / 48) & 3, dir = q / 192;
    const int j = ug * 12 + mt * 4 + (r16 >> 2);
    const int g = r16 & 3;
    const int row = g * 48 + j;
    bsum[q] = dir ? (bi_bw[row] + bh_bw[row]) : (bi_fw[row] + bh_fw[row]);
  } else if (t < 39296) {
    const int q = t - 37248;
    const int i = q & 7, lane = (q >> 3) & 63, fid = q >> 9;
    const int k = ((lane >> 4) << 3) + i;
    const int r16 = lane & 15;
    float v = 0.0f;
    if (fid == 0) {
      if (r16 < 12 && k >= 12 && k < 24) v = msg_w[r16 * 12 + (k - 12)];
    } else {
      const int R = (fid - 1) * 16 + r16;
      const int kind = R / 12, j = R % 12;
      if (kind == 0)      v = (k < 12) ? gw_ih[j * 12 + k]          : ((k < 24) ? gw_hh[j * 12 + (k - 12)] : 0.0f);
      else if (kind == 1) v = (k < 12) ? gw_ih[(12 + j) * 12 + k]   : ((k < 24) ? gw_hh[(12 + j) * 12 + (k - 12)] : 0.0f);
      else if (kind == 2) v = (k < 12) ? gw_ih[(24 + j) * 12 + k]   : 0.0f;
      else                v = (k >= 12 && k < 24) ? gw_hh[(24 + j) * 12 + (k - 12)] : 0.0f;
    }
    mfrag[q] = __builtin_bit_cast(unsigned short, (_Float16)v);
  } else if (t < 39360) {
    const int q = t - 39296;
    if (q < 16) mbias[q] = (q < 12) ? msg_b[q] : 0.0f;
    else {
      const int R = q - 16, kind = R / 12, j = R % 12;
      float v;
      if (kind == 0)      v = gb_ih[j] + gb_hh[j];
      else if (kind == 1) v = gb_ih[12 + j] + gb_hh[12 + j];
      else if (kind == 2) v = gb_ih[24 + j];
      else                v = gb_hh[24 + j];
      mbias[q] = v;
    }
  }
}

// ---------------------------------------------------------------------------
// Phase A via MFMA. NEW (vs r9): epilogue rewritten — final-pass h goes to a
// sample-major xbuf (aliases dead g_lds; gate reads hoisted + barrier), and
// the store reads xbuf[lane*50+f] (bank 25*lane mod 32, odd stride ->
// conflict-free). The old transpose-read B_lds[cg][12+d] was a 32-way bank
// conflict (4*20*q mod 32 = 16q -> 2 banks for 64 lanes), ~19us/CU of the
// 11.6M conflict cycles seen in r9. Zero-init trimmed to the 10 dwords read.
// ---------------------------------------------------------------------------
__global__ __launch_bounds__(256) void msg_mfma_kernel(
    const float* __restrict__ nf, const float* __restrict__ pos,
    const float* __restrict__ att,
    const unsigned short* __restrict__ mfrag, const float* __restrict__ mbias,
    unsigned short* __restrict__ xth)
{
  __shared__ unsigned short B_lds[256][40];   // f16 bits, 80B rows
  __shared__ unsigned short g_lds[256][50];   // f16 bits, 100B rows
  unsigned short* xbuf = &g_lds[0][0];        // [64][50] alias (final pass only)

  const int tid  = threadIdx.x;
  const int lane = tid & 63;
  const int w    = __builtin_amdgcn_readfirstlane(tid >> 6);
  const int c16  = lane & 15;
  const int grp  = lane >> 4;
  const int own  = tid;
  const int node = own & 3;
  const int sl   = (own >> 6) * 16 + ((own >> 4) & 3) * 4 + ((own >> 2) & 3);

  half8 A1 = *reinterpret_cast<const half8*>(mfrag + (size_t)lane * 8);
  half8 A2[3];
#pragma unroll
  for (int mt = 0; mt < 3; ++mt)
    A2[mt] = *reinterpret_cast<const half8*>(mfrag + (size_t)((1 + mt) * 64 + lane) * 8);
  const f32x4 bias1 = *reinterpret_cast<const f32x4*>(mbias + grp * 4);
  f32x4 bias2[3];
#pragma unroll
  for (int mt = 0; mt < 3; ++mt)
    bias2[mt] = *reinterpret_cast<const f32x4*>(mbias + 16 + mt * 16 + grp * 4);

  // zero only the dwords GEMM1/GEMM2 read before they are written:
  // dw 0..5 = mv region (read by GEMM1 pass 0), dw 12..15 = k=24..31 pad.
  {
    unsigned int* bz = reinterpret_cast<unsigned int*>(&B_lds[0][0]);
#pragma unroll
    for (int q = 0; q < 6; ++q)  bz[tid * 20 + q] = 0u;
#pragma unroll
    for (int q = 12; q < 16; ++q) bz[tid * 20 + q] = 0u;
  }

  const int sid = blockIdx.x * 64 + sl;
  const int s   = sid >> 16;
  const int b   = sid & (NB - 1);
  float h[12];
  {
    const size_t ib = ((size_t)(b * SL + s) * 4 + node) * 6;
    const float2* n2 = (const float2*)(nf  + ib);
    const float2* p2 = (const float2*)(pos + ib);
#pragma unroll
    for (int q = 0; q < 3; q++) {
      float2 v = n2[q]; h[q*2]   = v.x; h[q*2+1]   = v.y;
      float2 u = p2[q]; h[6+q*2] = u.x; h[6+q*2+1] = u.y;
    }
  }
  float ta[4];
  {
    float4 v = *(const float4*)(att + ((size_t)(b * SL + s) * 4 + node) * 4);
    ta[0] = v.x; ta[1] = v.y; ta[2] = v.z; ta[3] = v.w;
  }
  {
    unsigned int* bp = (unsigned int*)&B_lds[own][0];
#pragma unroll
    for (int d = 0; d < 6; ++d) bp[6 + d] = pkh2(h[2*d], h[2*d+1]);
  }
  __syncthreads();

#pragma unroll 1
  for (int pass = 0; pass < 2; ++pass) {
    // --- GEMM1: m_all (rows 0..11) ---
#pragma unroll
    for (int nt = 0; nt < 4; ++nt) {
      const int col = w * 64 + nt * 16 + c16;
      half8 B = *reinterpret_cast<const half8*>(&B_lds[col][grp * 8]);
      f32x4 C = __builtin_amdgcn_mfma_f32_16x16x32_f16(A1, B, bias1, 0, 0, 0);
      if (grp < 3) {
        unsigned int* gp = (unsigned int*)&g_lds[col][0];
        gp[grp * 2]     = pkh2(C[0], C[1]);
        gp[grp * 2 + 1] = pkh2(C[2], C[3]);
      }
    }
    __syncthreads();

    // --- attention mix (paired u32 reads; quad-broadcast) ---
    {
      const int cb = own & ~3;
      float mv[12];
#pragma unroll
      for (int d = 0; d < 12; ++d) mv[d] = 0.0f;
#pragma unroll
      for (int ww = 0; ww < 4; ++ww) {
        const float a = ta[ww];
        const unsigned int* gp = (const unsigned int*)&g_lds[cb + ww][0];
#pragma unroll
        for (int dq = 0; dq < 6; ++dq) {
          const unsigned int u = gp[dq];
          mv[2*dq]   = __builtin_fmaf(a, loh(u), mv[2*dq]);
          mv[2*dq+1] = __builtin_fmaf(a, hih(u), mv[2*dq+1]);
        }
      }
      unsigned int* bp = (unsigned int*)&B_lds[own][0];
#pragma unroll
      for (int d = 0; d < 6; ++d) bp[d] = pkh2(mv[2*d], mv[2*d+1]);
    }
    __syncthreads();

    // --- GEMM2: gates, 48 rows = [r | z | n_ih | n_hh] ---
#pragma unroll
    for (int nt = 0; nt < 4; ++nt) {
      const int col = w * 64 + nt * 16 + c16;
      half8 B = *reinterpret_cast<const half8*>(&B_lds[col][grp * 8]);
      f32x4 C0 = __builtin_amdgcn_mfma_f32_16x16x32_f16(A2[0], B, bias2[0], 0, 0, 0);
      f32x4 C1 = __builtin_amdgcn_mfma_f32_16x16x32_f16(A2[1], B, bias2[1], 0, 0, 0);
      f32x4 C2 = __builtin_amdgcn_mfma_f32_16x16x32_f16(A2[2], B, bias2[2], 0, 0, 0);
      unsigned int* gp = (unsigned int*)&g_lds[col][0];
      gp[grp * 2]      = pkh2(C0[0], C0[1]);
      gp[grp * 2 + 1]  = pkh2(C0[2], C0[3]);
      gp[8 + grp * 2]     = pkh2(C1[0], C1[1]);
      gp[8 + grp * 2 + 1] = pkh2(C1[2], C1[3]);
      gp[16 + grp * 2]     = pkh2(C2[0], C2[1]);
      gp[16 + grp * 2 + 1] = pkh2(C2[2], C2[3]);
    }
    __syncthreads();

    // --- GRU update (gate reads hoisted; pass 1 writes to xbuf) ---
    {
      unsigned int ur[6], uz[6], ui[6], uh[6];
      const unsigned int* gq = (const unsigned int*)&g_lds[own][0];
#pragma unroll
      for (int jq = 0; jq < 6; ++jq) {
        ur[jq] = gq[jq];
        uz[jq] = gq[6 + jq];
        ui[jq] = gq[12 + jq];
        uh[jq] = gq[18 + jq];
      }
      if (pass) __syncthreads();   // xbuf aliases g_lds: all gate reads done
#pragma unroll
      for (int jq = 0; jq < 6; ++jq) {
        {
          const float r = sigm(loh(ur[jq])), z = sigm(loh(uz[jq]));
          const float g = tanh_f(loh(ui[jq]) + r * loh(uh[jq]));
          h[2*jq] = (1.0f - z) * g + z * h[2*jq];
        }
        {
          const float r = sigm(hih(ur[jq])), z = sigm(hih(uz[jq]));
          const float g = tanh_f(hih(ui[jq]) + r * hih(uh[jq]));
          h[2*jq+1] = (1.0f - z) * g + z * h[2*jq+1];
        }
      }
      if (pass == 0) {
        unsigned int* bp = (unsigned int*)&B_lds[own][0];
#pragma unroll
        for (int d = 0; d < 6; ++d) bp[6 + d] = pkh2(h[2*d], h[2*d+1]);
      } else {
        // sample-major xbuf[sl][f=d*4+node]; banks 25*sl+2d+node/2 -> spread
#pragma unroll
        for (int d = 0; d < 12; ++d)
          xbuf[sl * 50 + d * 4 + node] =
              __builtin_bit_cast(unsigned short, (_Float16)h[d]);
      }
    }
    __syncthreads();
  }

  // --- store: lane i = batch b0+i reads xbuf[i*50+f] (conflict-free) ---
  const int b0   = (blockIdx.x * 64) & (NB - 1);
  const int sblk = blockIdx.x >> 10;           // block-uniform s
#pragma unroll
  for (int ff = 0; ff < 12; ++ff) {
    const int f = w * 12 + ff;
    xth[(size_t)(sblk * 48 + f) * NB + b0 + lane] = xbuf[lane * 50 + f];
  }
}

// ---------------------------------------------------------------------------
// Phase B+C: biLSTM via MFMA + MLP head (unchanged from round 9).
// ---------------------------------------------------------------------------
__global__ __launch_bounds__(512) void lstm_mfma_kernel(
    const unsigned short* __restrict__ xth,
    const unsigned short* __restrict__ wfrag,
    const float* __restrict__ bsum,
    const float* __restrict__ e1w, const float* __restrict__ e1b,
    const float* __restrict__ e2w, const float* __restrict__ e2b,
    const float* __restrict__ e3w, const float* __restrict__ e3b,
    float* __restrict__ out)
{
  __shared__ float4 pool4[2496];               // 39936 B
  float* pool = (float*)pool4;
  unsigned short* act = (unsigned short*)pool; // [2][64][104] halfs (26624 B)
  float* hf  = pool;                           // [64][100] f32 (aliases act; after loop)
  float* e1o = pool + 6656;                    // [64][52] f32
  float* e2o = pool;                           // [64][44] f32 (aliases hf; after e1)

  const int tid  = threadIdx.x;
  const int lane = tid & 63;
  const int w    = __builtin_amdgcn_readfirstlane(tid >> 6);
  const int dir  = w & 1;
  const int ug   = w >> 1;
  const int b0   = blockIdx.x * 64;
  const int col  = lane & 15;
  const int grp  = lane >> 4;

  half8 A[3][3];
#pragma unroll
  for (int mt = 0; mt < 3; ++mt)
#pragma unroll
    for (int kc = 0; kc < 3; ++kc) {
      const int fid = ((dir * 4 + ug) * 3 + mt) * 3 + kc;
      A[mt][kc] = *reinterpret_cast<const half8*>(wfrag + (size_t)(fid * 64 + lane) * 8);
    }
  f32x4 bias[3];
#pragma unroll
  for (int mt = 0; mt < 3; ++mt)
    bias[mt] = *reinterpret_cast<const f32x4*>(bsum + ((dir * 4 + ug) * 3 + mt) * 16 + grp * 4);

#pragma unroll
  for (int ff = 0; ff < 6; ++ff) {
    const int f = w * 6 + ff;
    act[(0 * 64 + lane) * 104 + f] = xth[(size_t)(0 * 48 + f) * NB + b0 + lane];
    act[(1 * 64 + lane) * 104 + f] = xth[(size_t)(4 * 48 + f) * NB + b0 + lane];
  }
#pragma unroll
  for (int jj = 0; jj < 12; ++jj)
    act[(dir * 64 + lane) * 104 + 48 + ug * 12 + jj] = 0;
  __syncthreads();

  float c[3][4];
#pragma unroll
  for (int mt = 0; mt < 3; ++mt)
#pragma unroll
    for (int nt = 0; nt < 4; ++nt) c[mt][nt] = 0.0f;

#pragma unroll 1
  for (int st = 0; st < 5; ++st) {
    float hvf[3][4];
#pragma unroll
    for (int nt = 0; nt < 4; ++nt) {
      const int n = nt * 16 + col;
      const unsigned short* ar = &act[(dir * 64 + n) * 104];
      half8 B0 = *reinterpret_cast<const half8*>(ar + grp * 8);
      half8 B1 = *reinterpret_cast<const half8*>(ar + 32 + grp * 8);
      half8 B2 = *reinterpret_cast<const half8*>(ar + 64 + grp * 8);
      f32x4 C0 = bias[0], C1 = bias[1], C2 = bias[2];
      C0 = __builtin_amdgcn_mfma_f32_16x16x32_f16(A[0][0], B0, C0, 0, 0, 0);
      C0 = __builtin_amdgcn_mfma_f32_16x16x32_f16(A[0][1], B1, C0, 0, 0, 0);
      C0 = __builtin_amdgcn_mfma_f32_16x16x32_f16(A[0][2], B2, C0, 0, 0, 0);
      C1 = __builtin_amdgcn_mfma_f32_16x16x32_f16(A[1][0], B0, C1, 0, 0, 0);
      C1 = __builtin_amdgcn_mfma_f32_16x16x32_f16(A[1][1], B1, C1, 0, 0, 0);
      C1 = __builtin_amdgcn_mfma_f32_16x16x32_f16(A[1][2], B2, C1, 0, 0, 0);
      C2 = __builtin_amdgcn_mfma_f32_16x16x32_f16(A[2][0], B0, C2, 0, 0, 0);
      C2 = __builtin_amdgcn_mfma_f32_16x16x32_f16(A[2][1], B1, C2, 0, 0, 0);
      C2 = __builtin_amdgcn_mfma_f32_16x16x32_f16(A[2][2], B2, C2, 0, 0, 0);
#pragma unroll
      for (int mt = 0; mt < 3; ++mt) {
        const f32x4 C = (mt == 0) ? C0 : (mt == 1) ? C1 : C2;
        const float cc = sigm(C[1]) * c[mt][nt] + sigm(C[0]) * tanh_f(C[2]);
        c[mt][nt] = cc;
        hvf[mt][nt] = sigm(C[3]) * tanh_f(cc);
      }
    }
    __syncthreads();                       // all act reads complete
    if (st < 4) {
#pragma unroll
      for (int mt = 0; mt < 3; ++mt)
#pragma unroll
        for (int nt = 0; nt < 4; ++nt)
          act[(dir * 64 + nt * 16 + col) * 104 + 48 + ug * 12 + mt * 4 + grp] =
              __builtin_bit_cast(unsigned short, (_Float16)hvf[mt][nt]);
      const int s0 = st + 1, s1 = 3 - st;
#pragma unroll
      for (int ff = 0; ff < 6; ++ff) {
        const int f = w * 6 + ff;
        act[(0 * 64 + lane) * 104 + f] = xth[(size_t)(s0 * 48 + f) * NB + b0 + lane];
        act[(1 * 64 + lane) * 104 + f] = xth[(size_t)(s1 * 48 + f) * NB + b0 + lane];
      }
    } else {
      // final h -> f32 batch-major hf[64][100]
#pragma unroll
      for (int mt = 0; mt < 3; ++mt)
#pragma unroll
        for (int nt = 0; nt < 4; ++nt)
          hf[(nt * 16 + col) * 100 + dir * 48 + ug * 12 + mt * 4 + grp] = hvf[mt][nt];
    }
    __syncthreads();
  }

  // ---- MLP head: float4 activation reads, accumulators hoisted ----
  {
    float acc[6];
#pragma unroll
    for (int r = 0; r < 6; ++r) acc[r] = e1b[w * 6 + r];
#pragma unroll
    for (int q = 0; q < 24; ++q) {
      const float4 v = *reinterpret_cast<const float4*>(&hf[lane * 100 + q * 4]);
#pragma unroll
      for (int r = 0; r < 6; ++r) {
        const int rr = w * 6 + r;
        acc[r] = __builtin_fmaf(e1w[rr * 96 + q * 4 + 0], v.x, acc[r]);
        acc[r] = __builtin_fmaf(e1w[rr * 96 + q * 4 + 1], v.y, acc[r]);
        acc[r] = __builtin_fmaf(e1w[rr * 96 + q * 4 + 2], v.z, acc[r]);
        acc[r] = __builtin_fmaf(e1w[rr * 96 + q * 4 + 3], v.w, acc[r]);
      }
    }
    __syncthreads();
#pragma unroll
    for (int r = 0; r < 6; ++r)
      e1o[lane * 52 + w * 6 + r] = acc[r] > 0.0f ? acc[r] : 0.0f;
  }
  __syncthreads();

  {
    const int e2base = (w < 4) ? w * 5 : 20 + (w - 4) * 4;
    const int e2cnt  = (w < 4) ? 5 : 4;
    float acc[5];
#pragma unroll
    for (int r = 0; r < 5; ++r) acc[r] = (r < e2cnt) ? e2b[e2base + r] : 0.0f;
#pragma unroll
    for (int q = 0; q < 12; ++q) {
      const float4 v = *reinterpret_cast<const float4*>(&e1o[lane * 52 + q * 4]);
#pragma unroll
      for (int r = 0; r < 5; ++r) {
        if (r < e2cnt) {
          const int rr = e2base + r;
          acc[r] = __builtin_fmaf(e2w[rr * 48 + q * 4 + 0], v.x, acc[r]);
          acc[r] = __builtin_fmaf(e2w[rr * 48 + q * 4 + 1], v.y, acc[r]);
          acc[r] = __builtin_fmaf(e2w[rr * 48 + q * 4 + 2], v.z, acc[r]);
          acc[r] = __builtin_fmaf(e2w[rr * 48 + q * 4 + 3], v.w, acc[r]);
        }
      }
    }
    __syncthreads();
#pragma unroll
    for (int r = 0; r < 5; ++r)
      if (r < e2cnt) e2o[lane * 44 + e2base + r] = acc[r] > 0.0f ? acc[r] : 0.0f;
  }
  __syncthreads();

  if (w < 6) {
    float a = e3b[w];
#pragma unroll
    for (int q = 0; q < 9; ++q) {
      const float4 v = *reinterpret_cast<const float4*>(&e2o[lane * 44 + q * 4]);
      a = __builtin_fmaf(e3w[w * 36 + q * 4 + 0], v.x, a);
      a = __builtin_fmaf(e3w[w * 36 + q * 4 + 1], v.y, a);
      a = __builtin_fmaf(e3w[w * 36 + q * 4 + 2], v.z, a);
      a = __builtin_fmaf(e3w[w * 36 + q * 4 + 3], v.w, a);
    }
    out[(size_t)(b0 + lane) * 6 + w] = a;
  }
}

extern "C" void kernel_launch(void* const* d_in, const int* in_sizes, int n_in,
                              void* d_out, int out_size, void* d_ws, size_t ws_size,
                              hipStream_t stream)
{
  const float* nf    = (const float*)d_in[0];
  const float* pos   = (const float*)d_in[1];
  const float* att   = (const float*)d_in[2];
  const float* msg_w = (const float*)d_in[3];
  const float* msg_b = (const float*)d_in[4];
  const float* gw_ih = (const float*)d_in[5];
  const float* gw_hh = (const float*)d_in[6];
  const float* gb_ih = (const float*)d_in[7];
  const float* gb_hh = (const float*)d_in[8];
  const float* wi_fw = (const float*)d_in[9];
  const float* wh_fw = (const float*)d_in[10];
  const float* bi_fw = (const float*)d_in[11];
  const float* bh_fw = (const float*)d_in[12];
  const float* wi_bw = (const float*)d_in[13];
  const float* wh_bw = (const float*)d_in[14];
  const float* bi_bw = (const float*)d_in[15];
  const float* bh_bw = (const float*)d_in[16];
  const float* e1w   = (const float*)d_in[17];
  const float* e1b   = (const float*)d_in[18];
  const float* e2w   = (const float*)d_in[19];
  const float* e2b   = (const float*)d_in[20];
  const float* e3w   = (const float*)d_in[21];
  const float* e3b   = (const float*)d_in[22];

  unsigned short* xth   = (unsigned short*)d_ws;
  unsigned short* wfrag = xth + (size_t)SL * 48 * NB;
  float*          bsum  = (float*)(wfrag + 36864);
  unsigned short* mfrag = (unsigned short*)(bsum + 384);
  float*          mbias = (float*)(mfrag + 2048);
  float*          outp  = (float*)d_out;

  prep_kernel<<<154, 256, 0, stream>>>(
      wi_fw, wh_fw, bi_fw, bh_fw, wi_bw, wh_bw, bi_bw, bh_bw,
      msg_w, msg_b, gw_ih, gw_hh, gb_ih, gb_hh,
      wfrag, bsum, mfrag, mbias);

  msg_mfma_kernel<<<(NB * SL) / 64, 256, 0, stream>>>(
      nf, pos, att, mfrag, mbias, xth);

  lstm_mfma_kernel<<<NB / 64, 512, 0, stream>>>(
      xth, wfrag, bsum, e1w, e1b, e2w, e2b, e3w, e3b, outp);
}